// Round 9
// baseline (609.618 us; speedup 1.0000x reference)
//
#include <hip/hip_runtime.h>

#define NN 100000
#define NE 3200000
#define NG 128
#define HID 64
#define OUTC 128

#define CHUNK 8192
#define NBLK 391                 // ceil(NE / CHUNK)
#define NB1 782                  // ceil(NN / 128) coarse buckets (dst >> 7)

typedef _Float16 half2v __attribute__((ext_vector_type(2)));
typedef _Float16 half4v __attribute__((ext_vector_type(4)));
typedef _Float16 half8v __attribute__((ext_vector_type(8)));
typedef float f32x4 __attribute__((ext_vector_type(4)));

// ---------------- P1: per-block coarse histogram (LDS atomics only) ----------------
__global__ __launch_bounds__(256) void k_hist(const int* __restrict__ dst,
                                              int* __restrict__ hist1) {
    __shared__ int h[NB1];
    for (int i = threadIdx.x; i < NB1; i += 256) h[i] = 0;
    __syncthreads();
    int base = blockIdx.x * CHUNK;
    int end = min(base + CHUNK, NE);
    for (int e = base + threadIdx.x; e < end; e += 256)
        atomicAdd(&h[dst[e] >> 7], 1);
    __syncthreads();
    for (int i = threadIdx.x; i < NB1; i += 256)
        hist1[i * NBLK + blockIdx.x] = h[i];
}

// ---------------- P2a: per-row totals (one wave per row) ----------------
__global__ __launch_bounds__(256) void k_rowsum(const int* __restrict__ hist1,
                                                int* __restrict__ rowtot) {
    int row = blockIdx.x * 4 + (threadIdx.x >> 6);
    int lane = threadIdx.x & 63;
    if (row >= NB1) return;
    int s = 0;
    for (int k = lane; k < NBLK; k += 64) s += hist1[row * NBLK + k];
#pragma unroll
    for (int m = 1; m < 64; m <<= 1) s += __shfl_xor(s, m);
    if (lane == 0) rowtot[row] = s;
}

// ---------------- P2b: small single-block scan of 782 row totals ----------------
__global__ __launch_bounds__(1024) void k_scanb(const int* __restrict__ rowtot,
                                                int* __restrict__ rowbase,
                                                int* __restrict__ bb) {
    __shared__ int sums[1024];
    int t = threadIdx.x;
    int v = (t < NB1) ? rowtot[t] : 0;
    sums[t] = v;
    __syncthreads();
    for (int d = 1; d < 1024; d <<= 1) {
        int u = (t >= d) ? sums[t - d] : 0;
        __syncthreads();
        sums[t] += u;
        __syncthreads();
    }
    if (t < NB1) {
        int base = sums[t] - v;   // exclusive
        rowbase[t] = base;
        bb[t] = base;
    }
    if (t == 0) bb[NB1] = NE;
}

// ---------------- P2c: per-row exclusive scan (one wave per row) ----------------
__global__ __launch_bounds__(256) void k_rowscan(int* __restrict__ hist1,
                                                 const int* __restrict__ rowbase) {
    int row = blockIdx.x * 4 + (threadIdx.x >> 6);
    int lane = threadIdx.x & 63;
    if (row >= NB1) return;
    int carry = rowbase[row];
    for (int k0 = 0; k0 < NBLK; k0 += 64) {
        int k = k0 + lane;
        int v = (k < NBLK) ? hist1[row * NBLK + k] : 0;
        int xv = v;
#pragma unroll
        for (int m = 1; m < 64; m <<= 1) {
            int y = __shfl_up(xv, m);
            if (lane >= m) xv += y;
        }
        int tot = __shfl(xv, 63);
        if (k < NBLK) hist1[row * NBLK + k] = xv - v + carry;
        carry += tot;
    }
}

// ---------------- P3: scatter into coarse buckets (LDS cursors) ----------------
__global__ __launch_bounds__(256) void k_scat(const int* __restrict__ src,
                                              const int* __restrict__ dst,
                                              const int* __restrict__ hist1,
                                              int* __restrict__ packed) {
    __shared__ int cur[NB1];
    for (int i = threadIdx.x; i < NB1; i += 256)
        cur[i] = hist1[i * NBLK + blockIdx.x];
    __syncthreads();
    int base = blockIdx.x * CHUNK;
    int end = min(base + CHUNK, NE);
    for (int e = base + threadIdx.x; e < end; e += 256) {
        int d = dst[e], s = src[e];
        int p = atomicAdd(&cur[d >> 7], 1);
        packed[p] = ((d & 127) << 17) | s;   // src < 2^17
    }
}

// ---------------- P4: within-bucket group by exact dst; emit neigh + off ----------------
__global__ __launch_bounds__(256) void k_bucket(const int* __restrict__ packed,
                                                const int* __restrict__ bb,
                                                int* __restrict__ neigh,
                                                int* __restrict__ off) {
    int b = blockIdx.x;
    int lo = bb[b], hi = bb[b + 1];
    __shared__ int cnt[128];
    __shared__ int pos[128];
    __shared__ int cur2[128];
    if (threadIdx.x < 128) cnt[threadIdx.x] = 0;
    __syncthreads();
    for (int i = lo + threadIdx.x; i < hi; i += 256)
        atomicAdd(&cnt[packed[i] >> 17], 1);
    __syncthreads();
    if (threadIdx.x == 0) {
        int run = lo;
        for (int j = 0; j < 128; ++j) { pos[j] = run; run += cnt[j]; }
    }
    __syncthreads();
    if (threadIdx.x < 128) {
        int node = b * 128 + threadIdx.x;
        if (node <= NN) off[node] = pos[threadIdx.x];
        cur2[threadIdx.x] = pos[threadIdx.x];
    }
    __syncthreads();
    for (int i = lo + threadIdx.x; i < hi; i += 256) {
        int p = packed[i];
        int j = p >> 17;
        int q = atomicAdd(&cur2[j], 1);
        neigh[q] = p & 0x1FFFF;
    }
}

// ---------------- layer 1: CSR mean-agg (d=3) + transform, fp16 out ----------------
__global__ __launch_bounds__(256) void k_l1(const int* __restrict__ off,
                                            const int* __restrict__ neigh,
                                            const float* __restrict__ x,
                                            const float* __restrict__ Wl,
                                            const float* __restrict__ bl,
                                            const float* __restrict__ Wr,
                                            _Float16* __restrict__ out) {
    int n = blockIdx.x * 4 + (threadIdx.x >> 6);
    int c = threadIdx.x & 63;
    if (n >= NN) return;
    int lo = off[n], hi = off[n + 1];
    float a0 = 0.f, a1 = 0.f, a2 = 0.f;
    for (int i = lo + c; i < hi; i += 64) {
        int s = neigh[i];
        a0 += x[s * 3 + 0];
        a1 += x[s * 3 + 1];
        a2 += x[s * 3 + 2];
    }
#pragma unroll
    for (int m = 1; m < 64; m <<= 1) {
        a0 += __shfl_xor(a0, m);
        a1 += __shfl_xor(a1, m);
        a2 += __shfl_xor(a2, m);
    }
    float ic = 1.0f / fmaxf((float)(hi - lo), 1.0f);
    a0 *= ic; a1 *= ic; a2 *= ic;
    float x0 = x[n * 3 + 0], x1 = x[n * 3 + 1], x2 = x[n * 3 + 2];
    float acc = bl[c]
              + a0 * Wl[0 * 64 + c] + a1 * Wl[1 * 64 + c] + a2 * Wl[2 * 64 + c]
              + x0 * Wr[0 * 64 + c] + x1 * Wr[1 * 64 + c] + x2 * Wr[2 * 64 + c];
    out[(size_t)n * 64 + c] = (_Float16)fmaxf(acc, 0.0f);
}

// ---------------- fused layer: quad-gather + MFMA transform ----------------
// One wave = 16 nodes. A-tile [16][mean(64)|root(64)] in wave-private LDS,
// transform = 16 x mfma_f32_16x16x32_f16 vs W-frags held in VGPRs.
// h: fp16 [NN][64]; out must not alias h. No block barrier needed.
__global__ __launch_bounds__(256, 4) void k_layer(const int* __restrict__ off,
                                                  const int* __restrict__ neigh,
                                                  const _Float16* __restrict__ h,
                                                  const float* __restrict__ Wl,
                                                  const float* __restrict__ bl,
                                                  const float* __restrict__ Wr,
                                                  _Float16* __restrict__ out) {
    // A rows padded 128->136 f16 (272B stride) => ~2-way-conflict frag reads
    __shared__ __align__(16) _Float16 Asl[4][16][136];

    const int li   = threadIdx.x >> 6;
    const int lane = threadIdx.x & 63;
    const int g    = lane >> 4;          // quad group / k-group
    const int q    = lane & 15;          // column quad / M index / N index
    const int wgid = blockIdx.x * 4 + li;
    const int nbase = wgid * 16;
    if (nbase >= NN) return;             // NN % 16 == 0: full waves only

    // ---- W-fragment + bias preload (once per wave; stacked B[128][64] = [Wl;Wr]) ----
    // B-frag layout: n = lane&15 (per col-tile), k = (lane>>4)*8 + e
    half8v bfr[4][4];
    float bias[4];
#pragma unroll
    for (int t = 0; t < 4; ++t) {
        int c = 16 * t + q;
        bias[t] = bl[c];
#pragma unroll
        for (int s = 0; s < 4; ++s) {
#pragma unroll
            for (int e = 0; e < 8; ++e) {
                int kk = 32 * s + g * 8 + e;
                float w = (kk < 64) ? Wl[kk * 64 + c] : Wr[(kk - 64) * 64 + c];
                bfr[t][s][e] = (_Float16)w;
            }
        }
    }

    const char* __restrict__ hb = (const char*)h;
    const unsigned qoff = (unsigned)q << 3;

    // ---- gather phase: 16 nodes, quad-mode (4 neighbors/iter, 8B/lane) ----
    for (int j = 0; j < 16; ++j) {
        int n = nbase + j;
        int lo = __builtin_amdgcn_readfirstlane(off[n]);
        int hi = __builtin_amdgcn_readfirstlane(off[n + 1]);
        int deg = hi - lo;
        const int* __restrict__ np = neigh + lo;

        float ax = 0.f, ay = 0.f, az = 0.f, aw = 0.f;
        int nq = deg >> 2;
#pragma unroll 4
        for (int i = 0; i < nq; ++i) {
            int s0 = np[4 * i + 0];      // uniform -> s_load
            int s1 = np[4 * i + 1];
            int s2 = np[4 * i + 2];
            int s3 = np[4 * i + 3];
            int s = (g & 2) ? ((g & 1) ? s3 : s2) : ((g & 1) ? s1 : s0);
            half4v v = *(const half4v*)(hb + (((unsigned)s << 7) | qoff));
            ax += (float)v.x; ay += (float)v.y; az += (float)v.z; aw += (float)v.w;
        }
        if (g == 0) {                    // tail: group 0 only
            for (int i = nq << 2; i < deg; ++i) {
                int s = np[i];
                half4v v = *(const half4v*)(hb + (((unsigned)s << 7) | qoff));
                ax += (float)v.x; ay += (float)v.y; az += (float)v.z; aw += (float)v.w;
            }
        }
#pragma unroll
        for (int m = 16; m <= 32; m <<= 1) {
            ax += __shfl_xor(ax, m);
            ay += __shfl_xor(ay, m);
            az += __shfl_xor(az, m);
            aw += __shfl_xor(aw, m);
        }
        if (g == 0) {                    // mean -> A[j][0..63]
            float ic = 1.0f / fmaxf((float)deg, 1.0f);
            *(half4v*)&Asl[li][j][4 * q] =
                half4v{(_Float16)(ax * ic), (_Float16)(ay * ic),
                       (_Float16)(az * ic), (_Float16)(aw * ic)};
        } else if (g == 1) {             // root -> A[j][64..127]
            half4v rv = *(const half4v*)(hb + (((unsigned)n << 7) | qoff));
            *(half4v*)&Asl[li][j][64 + 4 * q] = rv;
        }
    }
    // same-wave ds_write -> ds_read: hardware lgkmcnt ordering, no barrier

    // ---- MFMA transform: A[16][128] x B[128][64] ----
    // A-frag: m = q, k = 32s + g*8 + e (contiguous 8 -> ds_read_b128)
    half8v a0 = *(const half8v*)&Asl[li][q][0 * 32 + 8 * g];
    half8v a1 = *(const half8v*)&Asl[li][q][1 * 32 + 8 * g];
    half8v a2 = *(const half8v*)&Asl[li][q][2 * 32 + 8 * g];
    half8v a3 = *(const half8v*)&Asl[li][q][3 * 32 + 8 * g];

    f32x4 acc[4];
#pragma unroll
    for (int t = 0; t < 4; ++t) {
        acc[t] = f32x4{0.f, 0.f, 0.f, 0.f};
        acc[t] = __builtin_amdgcn_mfma_f32_16x16x32_f16(a0, bfr[t][0], acc[t], 0, 0, 0);
        acc[t] = __builtin_amdgcn_mfma_f32_16x16x32_f16(a1, bfr[t][1], acc[t], 0, 0, 0);
        acc[t] = __builtin_amdgcn_mfma_f32_16x16x32_f16(a2, bfr[t][2], acc[t], 0, 0, 0);
        acc[t] = __builtin_amdgcn_mfma_f32_16x16x32_f16(a3, bfr[t][3], acc[t], 0, 0, 0);
    }

    // ---- epilogue: C[m= g*4+r][n= q] per tile; bias + relu + fp16 store ----
#pragma unroll
    for (int t = 0; t < 4; ++t) {
        int col = 16 * t + q;
#pragma unroll
        for (int r = 0; r < 4; ++r) {
            int nl = g * 4 + r;
            float val = acc[t][r] + bias[t];
            out[(size_t)(nbase + nl) * 64 + col] = (_Float16)fmaxf(val, 0.0f);
        }
    }
}

// ---------------- pooling helpers ----------------
__device__ __forceinline__ int lower_bound_batch(const int* __restrict__ batch, int val) {
    int lo = 0, hi = NN;
    while (lo < hi) {
        int mid = (lo + hi) >> 1;
        if (batch[mid] < val) lo = mid + 1; else hi = mid;
    }
    return lo;
}

__global__ __launch_bounds__(64) void k_pool(const _Float16* __restrict__ h,
                                             const int* __restrict__ batch,
                                             float* __restrict__ psum) {
    int g = blockIdx.x >> 3;
    int part = blockIdx.x & 7;
    int lane = threadIdx.x;
    int lo = lower_bound_batch(batch, g);
    int hi = lower_bound_batch(batch, g + 1);
    float s = 0.0f;
    for (int n = lo + part; n < hi; n += 8) s += (float)h[(size_t)n * 64 + lane];
    atomicAdd(&psum[g * 64 + lane], s);
}

__global__ __launch_bounds__(128) void k_fc(const float* __restrict__ psum,
                                            const int* __restrict__ batch,
                                            const float* __restrict__ Wfc,
                                            const float* __restrict__ bfc,
                                            float* __restrict__ out) {
    __shared__ float meanv[64];
    __shared__ float red[2];
    int g = blockIdx.x;
    int c = threadIdx.x;
    int lo = lower_bound_batch(batch, g);
    int hi = lower_bound_batch(batch, g + 1);
    float icnt = 1.0f / fmaxf((float)(hi - lo), 1.0f);
    if (c < 64) meanv[c] = psum[g * 64 + c] * icnt;
    __syncthreads();
    float acc = bfc[c];
#pragma unroll
    for (int k = 0; k < 64; ++k) acc += meanv[k] * Wfc[k * 128 + c];
    float ss = acc * acc;
#pragma unroll
    for (int off = 32; off; off >>= 1) ss += __shfl_down(ss, off);
    if ((c & 63) == 0) red[c >> 6] = ss;
    __syncthreads();
    float norm = fmaxf(sqrtf(red[0] + red[1]), 1e-12f);
    out[g * 128 + c] = acc / norm;
}

extern "C" void kernel_launch(void* const* d_in, const int* in_sizes, int n_in,
                              void* d_out, int out_size, void* d_ws, size_t ws_size,
                              hipStream_t stream) {
    const float* x    = (const float*)d_in[0];
    const int*   ei   = (const int*)d_in[1];
    const int*   src  = ei;
    const int*   dst  = ei + NE;
    const int*   batch = (const int*)d_in[2];
    const float* Wl1 = (const float*)d_in[3];
    const float* bl1 = (const float*)d_in[4];
    const float* Wr1 = (const float*)d_in[5];
    const float* Wl2 = (const float*)d_in[6];
    const float* bl2 = (const float*)d_in[7];
    const float* Wr2 = (const float*)d_in[8];
    const float* Wl3 = (const float*)d_in[9];
    const float* bl3 = (const float*)d_in[10];
    const float* Wr3 = (const float*)d_in[11];
    const float* Wl4 = (const float*)d_in[12];
    const float* bl4 = (const float*)d_in[13];
    const float* Wr4 = (const float*)d_in[14];
    const float* Wfc = (const float*)d_in[15];
    const float* bfc = (const float*)d_in[16];
    float* out = (float*)d_out;

    // workspace layout
    _Float16* hA  = (_Float16*)d_ws;                  // [N,64] fp16
    _Float16* hB  = hA + (size_t)NN * 64;             // [N,64] fp16
    float* psum   = (float*)(hB + (size_t)NN * 64);   // [G,64]
    int*   off    = (int*)(psum + (size_t)NG * 64);   // [N+1]
    int*   bb     = off + NN + 1;                     // [NB1+1]
    int*   rowtot = bb + NB1 + 1;                     // [NB1]
    int*   rowbase = rowtot + NB1;                    // [NB1]
    int*   hist1  = rowbase + NB1;                    // [NB1*NBLK]
    int*   packed = hist1 + NB1 * NBLK;               // [E]
    int*   neigh  = packed + NE;                      // [E]

    hipMemsetAsync(psum, 0, (size_t)NG * 64 * sizeof(float), stream);

    // CSR build: atomic-free two-level bucket sort, fully parallel scan
    k_hist<<<NBLK, 256, 0, stream>>>(dst, hist1);
    k_rowsum<<<(NB1 + 3) / 4, 256, 0, stream>>>(hist1, rowtot);
    k_scanb<<<1, 1024, 0, stream>>>(rowtot, rowbase, bb);
    k_rowscan<<<(NB1 + 3) / 4, 256, 0, stream>>>(hist1, rowbase);
    k_scat<<<NBLK, 256, 0, stream>>>(src, dst, hist1, packed);
    k_bucket<<<NB1, 256, 0, stream>>>(packed, bb, neigh, off);

    // layer 1 (fused d=3 agg + transform), fp16 out
    k_l1<<<(NN + 3) / 4, 256, 0, stream>>>(off, neigh, x, Wl1, bl1, Wr1, hA);

    // layers 2-4: fused quad-gather + MFMA transform (ping-pong hA/hB)
    const int layerGrid = (NN + 63) / 64;   // 4 waves x 16 nodes per block
    k_layer<<<layerGrid, 256, 0, stream>>>(off, neigh, hA, Wl2, bl2, Wr2, hB);
    k_layer<<<layerGrid, 256, 0, stream>>>(off, neigh, hB, Wl3, bl3, Wr3, hA);
    k_layer<<<layerGrid, 256, 0, stream>>>(off, neigh, hA, Wl4, bl4, Wr4, hB);

    k_pool<<<NG * 8, 64, 0, stream>>>(hB, batch, psum);
    k_fc<<<NG, 128, 0, stream>>>(psum, batch, Wfc, bfc, out);
}

// Round 10
// 454.104 us; speedup vs baseline: 1.3425x; 1.3425x over previous
//
#include <hip/hip_runtime.h>

#define NN 100000
#define NE 3200000
#define NG 128
#define HID 64
#define OUTC 128

#define CHUNK 8192
#define NBLK 391                 // ceil(NE / CHUNK)
#define NB1 782                  // ceil(NN / 128) coarse buckets (dst >> 7)

typedef _Float16 half2v __attribute__((ext_vector_type(2)));
typedef _Float16 half4v __attribute__((ext_vector_type(4)));
typedef _Float16 half8v __attribute__((ext_vector_type(8)));

#if __has_builtin(__builtin_amdgcn_fdot2)
#define FDOT2(a, b, c) __builtin_amdgcn_fdot2((a), (b), (c), false)
#else
#define FDOT2(a, b, c) ((c) + (float)(a).x * (float)(b).x + (float)(a).y * (float)(b).y)
#endif

// ---------------- P1: per-block coarse histogram (LDS atomics only) ----------------
__global__ __launch_bounds__(256) void k_hist(const int* __restrict__ dst,
                                              int* __restrict__ hist1) {
    __shared__ int h[NB1];
    for (int i = threadIdx.x; i < NB1; i += 256) h[i] = 0;
    __syncthreads();
    int base = blockIdx.x * CHUNK;
    int end = min(base + CHUNK, NE);
    for (int e = base + threadIdx.x; e < end; e += 256)
        atomicAdd(&h[dst[e] >> 7], 1);
    __syncthreads();
    for (int i = threadIdx.x; i < NB1; i += 256)
        hist1[i * NBLK + blockIdx.x] = h[i];
}

// ---------------- P2a: per-row totals (one wave per row) ----------------
__global__ __launch_bounds__(256) void k_rowsum(const int* __restrict__ hist1,
                                                int* __restrict__ rowtot) {
    int row = blockIdx.x * 4 + (threadIdx.x >> 6);
    int lane = threadIdx.x & 63;
    if (row >= NB1) return;
    int s = 0;
    for (int k = lane; k < NBLK; k += 64) s += hist1[row * NBLK + k];
#pragma unroll
    for (int m = 1; m < 64; m <<= 1) s += __shfl_xor(s, m);
    if (lane == 0) rowtot[row] = s;
}

// ---------------- P2b: small single-block scan of 782 row totals ----------------
__global__ __launch_bounds__(1024) void k_scanb(const int* __restrict__ rowtot,
                                                int* __restrict__ rowbase,
                                                int* __restrict__ bb) {
    __shared__ int sums[1024];
    int t = threadIdx.x;
    int v = (t < NB1) ? rowtot[t] : 0;
    sums[t] = v;
    __syncthreads();
    for (int d = 1; d < 1024; d <<= 1) {
        int u = (t >= d) ? sums[t - d] : 0;
        __syncthreads();
        sums[t] += u;
        __syncthreads();
    }
    if (t < NB1) {
        int base = sums[t] - v;   // exclusive
        rowbase[t] = base;
        bb[t] = base;
    }
    if (t == 0) bb[NB1] = NE;
}

// ---------------- P2c: per-row exclusive scan (one wave per row) ----------------
__global__ __launch_bounds__(256) void k_rowscan(int* __restrict__ hist1,
                                                 const int* __restrict__ rowbase) {
    int row = blockIdx.x * 4 + (threadIdx.x >> 6);
    int lane = threadIdx.x & 63;
    if (row >= NB1) return;
    int carry = rowbase[row];
    for (int k0 = 0; k0 < NBLK; k0 += 64) {
        int k = k0 + lane;
        int v = (k < NBLK) ? hist1[row * NBLK + k] : 0;
        int xv = v;
#pragma unroll
        for (int m = 1; m < 64; m <<= 1) {
            int y = __shfl_up(xv, m);
            if (lane >= m) xv += y;
        }
        int tot = __shfl(xv, 63);
        if (k < NBLK) hist1[row * NBLK + k] = xv - v + carry;
        carry += tot;
    }
}

// ---------------- P3: scatter into coarse buckets (LDS cursors) ----------------
__global__ __launch_bounds__(256) void k_scat(const int* __restrict__ src,
                                              const int* __restrict__ dst,
                                              const int* __restrict__ hist1,
                                              int* __restrict__ packed) {
    __shared__ int cur[NB1];
    for (int i = threadIdx.x; i < NB1; i += 256)
        cur[i] = hist1[i * NBLK + blockIdx.x];
    __syncthreads();
    int base = blockIdx.x * CHUNK;
    int end = min(base + CHUNK, NE);
    for (int e = base + threadIdx.x; e < end; e += 256) {
        int d = dst[e], s = src[e];
        int p = atomicAdd(&cur[d >> 7], 1);
        packed[p] = ((d & 127) << 17) | s;   // src < 2^17
    }
}

// ---------------- P4: within-bucket group by exact dst; emit neigh + off ----------------
__global__ __launch_bounds__(256) void k_bucket(const int* __restrict__ packed,
                                                const int* __restrict__ bb,
                                                int* __restrict__ neigh,
                                                int* __restrict__ off) {
    int b = blockIdx.x;
    int lo = bb[b], hi = bb[b + 1];
    __shared__ int cnt[128];
    __shared__ int pos[128];
    __shared__ int cur2[128];
    if (threadIdx.x < 128) cnt[threadIdx.x] = 0;
    __syncthreads();
    for (int i = lo + threadIdx.x; i < hi; i += 256)
        atomicAdd(&cnt[packed[i] >> 17], 1);
    __syncthreads();
    if (threadIdx.x == 0) {
        int run = lo;
        for (int j = 0; j < 128; ++j) { pos[j] = run; run += cnt[j]; }
    }
    __syncthreads();
    if (threadIdx.x < 128) {
        int node = b * 128 + threadIdx.x;
        if (node <= NN) off[node] = pos[threadIdx.x];
        cur2[threadIdx.x] = pos[threadIdx.x];
    }
    __syncthreads();
    for (int i = lo + threadIdx.x; i < hi; i += 256) {
        int p = packed[i];
        int j = p >> 17;
        int q = atomicAdd(&cur2[j], 1);
        neigh[q] = p & 0x1FFFF;
    }
}

// ---------------- layer 1: CSR mean-agg (d=3) + transform, fp16 out ----------------
__global__ __launch_bounds__(256) void k_l1(const int* __restrict__ off,
                                            const int* __restrict__ neigh,
                                            const float* __restrict__ x,
                                            const float* __restrict__ Wl,
                                            const float* __restrict__ bl,
                                            const float* __restrict__ Wr,
                                            _Float16* __restrict__ out) {
    int n = blockIdx.x * 4 + (threadIdx.x >> 6);
    int c = threadIdx.x & 63;
    if (n >= NN) return;
    int lo = off[n], hi = off[n + 1];
    float a0 = 0.f, a1 = 0.f, a2 = 0.f;
    for (int i = lo + c; i < hi; i += 64) {
        int s = neigh[i];
        a0 += x[s * 3 + 0];
        a1 += x[s * 3 + 1];
        a2 += x[s * 3 + 2];
    }
#pragma unroll
    for (int m = 1; m < 64; m <<= 1) {
        a0 += __shfl_xor(a0, m);
        a1 += __shfl_xor(a1, m);
        a2 += __shfl_xor(a2, m);
    }
    float ic = 1.0f / fmaxf((float)(hi - lo), 1.0f);
    a0 *= ic; a1 *= ic; a2 *= ic;
    float x0 = x[n * 3 + 0], x1 = x[n * 3 + 1], x2 = x[n * 3 + 2];
    float acc = bl[c]
              + a0 * Wl[0 * 64 + c] + a1 * Wl[1 * 64 + c] + a2 * Wl[2 * 64 + c]
              + x0 * Wr[0 * 64 + c] + x1 * Wr[1 * 64 + c] + x2 * Wr[2 * 64 + c];
    out[(size_t)n * 64 + c] = (_Float16)fmaxf(acc, 0.0f);
}

// ---------------- fused layer: fp16 oct-gather + dot2 matvec ----------------
// h: fp16 [NN][64]; out: fp16 [NN][64]. out must not alias h.
// Gather: 8-lane groups, each lane owns 8 cols (16B = one row per group),
// 8 neighbors/iter, 4/2/1-unrolled load-then-accumulate pipeline.
__global__ __launch_bounds__(512, 8) void k_layer(const int* __restrict__ off,
                                                  const int* __restrict__ neigh,
                                                  const _Float16* __restrict__ h,
                                                  const float* __restrict__ Wl,
                                                  const float* __restrict__ bl,
                                                  const float* __restrict__ Wr,
                                                  _Float16* __restrict__ out) {
    __shared__ half2v Wpk[2][32][64];                  // 16 KiB: k-pair packed Wl, Wr
    __shared__ __align__(16) _Float16 rowsh[2][8][64]; // mean row, root row per wave
    for (int idx = threadIdx.x; idx < 32 * 64; idx += 512) {
        int kp = idx >> 6, c = idx & 63;
        Wpk[0][kp][c] = half2v{(_Float16)Wl[(2 * kp) * 64 + c],
                               (_Float16)Wl[(2 * kp + 1) * 64 + c]};
        Wpk[1][kp][c] = half2v{(_Float16)Wr[(2 * kp) * 64 + c],
                               (_Float16)Wr[(2 * kp + 1) * 64 + c]};
    }
    __syncthreads();                      // only barrier: Wpk ready

    int li = threadIdx.x >> 6;
    int lane = threadIdx.x & 63;
    int g = lane >> 3;                    // neighbor slot within oct (0..7)
    int q8 = lane & 7;                    // column oct (cols 8q8..8q8+7)
    int n = blockIdx.x * 8 + li;          // grid exact: 12500*8 = NN
    if (n >= NN) return;

    float ob = bl[lane];                  // hoisted

    int lo = __builtin_amdgcn_readfirstlane(off[n]);
    int hi = __builtin_amdgcn_readfirstlane(off[n + 1]);
    int deg = hi - lo;
    const int* __restrict__ np = neigh + lo;
    const char* __restrict__ hb = (const char*)h;
    unsigned qoff = (unsigned)q8 << 4;    // 16B per column-oct

    // early root-row load (consumed after gather; extra load in flight)
    half8v rv{};
    if (g == 1) rv = *(const half8v*)(hb + (((unsigned)n << 7) | qoff));

    float acc[8];
#pragma unroll
    for (int c = 0; c < 8; ++c) acc[c] = 0.f;

    int nq = deg >> 3;
    int i = 0;
    // main: 4 iterations in flight (4 x 16B/lane outstanding)
    for (; i + 4 <= nq; i += 4) {
        int s0 = np[8 * (i + 0) + g];
        int s1 = np[8 * (i + 1) + g];
        int s2 = np[8 * (i + 2) + g];
        int s3 = np[8 * (i + 3) + g];
        half8v v0 = *(const half8v*)(hb + (((unsigned)s0 << 7) | qoff));
        half8v v1 = *(const half8v*)(hb + (((unsigned)s1 << 7) | qoff));
        half8v v2 = *(const half8v*)(hb + (((unsigned)s2 << 7) | qoff));
        half8v v3 = *(const half8v*)(hb + (((unsigned)s3 << 7) | qoff));
#pragma unroll
        for (int c = 0; c < 8; ++c)
            acc[c] += ((float)v0[c] + (float)v1[c]) + ((float)v2[c] + (float)v3[c]);
    }
    if (i + 2 <= nq) {
        int s0 = np[8 * (i + 0) + g];
        int s1 = np[8 * (i + 1) + g];
        half8v v0 = *(const half8v*)(hb + (((unsigned)s0 << 7) | qoff));
        half8v v1 = *(const half8v*)(hb + (((unsigned)s1 << 7) | qoff));
#pragma unroll
        for (int c = 0; c < 8; ++c) acc[c] += (float)v0[c] + (float)v1[c];
        i += 2;
    }
    if (i < nq) {
        int s0 = np[8 * i + g];
        half8v v0 = *(const half8v*)(hb + (((unsigned)s0 << 7) | qoff));
#pragma unroll
        for (int c = 0; c < 8; ++c) acc[c] += (float)v0[c];
    }
    // tail (deg%8): group 0 only
    if (g == 0) {
        for (int t = nq << 3; t < deg; ++t) {
            int s = np[t];
            half8v v = *(const half8v*)(hb + (((unsigned)s << 7) | qoff));
#pragma unroll
            for (int c = 0; c < 8; ++c) acc[c] += (float)v[c];
        }
    }
    // butterfly over the 8 neighbor slots
#pragma unroll
    for (int m = 8; m <= 32; m <<= 1) {
#pragma unroll
        for (int c = 0; c < 8; ++c) acc[c] += __shfl_xor(acc[c], m);
    }

    if (g == 0) {                         // mean -> rowsh[0]
        float ic = 1.0f / fmaxf((float)deg, 1.0f);
        half8v mv;
#pragma unroll
        for (int c = 0; c < 8; ++c) mv[c] = (_Float16)(acc[c] * ic);
        *(half8v*)&rowsh[0][li][8 * q8] = mv;
    } else if (g == 1) {                  // root -> rowsh[1]
        *(half8v*)&rowsh[1][li][8 * q8] = rv;
    }
    // same-wave ds_write -> ds_read: hardware lgkmcnt ordering, no barrier

    float o = ob;
#pragma unroll
    for (int k2 = 0; k2 < 32; ++k2) {
        half2v m2 = *(const half2v*)&rowsh[0][li][2 * k2];
        half2v r2 = *(const half2v*)&rowsh[1][li][2 * k2];
        o = FDOT2(m2, Wpk[0][k2][lane], o);
        o = FDOT2(r2, Wpk[1][k2][lane], o);
    }
    out[(size_t)n * 64 + lane] = (_Float16)fmaxf(o, 0.0f);
}

// ---------------- pooling helpers ----------------
__device__ __forceinline__ int lower_bound_batch(const int* __restrict__ batch, int val) {
    int lo = 0, hi = NN;
    while (lo < hi) {
        int mid = (lo + hi) >> 1;
        if (batch[mid] < val) lo = mid + 1; else hi = mid;
    }
    return lo;
}

__global__ __launch_bounds__(64) void k_pool(const _Float16* __restrict__ h,
                                             const int* __restrict__ batch,
                                             float* __restrict__ psum) {
    int g = blockIdx.x >> 3;
    int part = blockIdx.x & 7;
    int lane = threadIdx.x;
    int lo = lower_bound_batch(batch, g);
    int hi = lower_bound_batch(batch, g + 1);
    float s = 0.0f;
    for (int n = lo + part; n < hi; n += 8) s += (float)h[(size_t)n * 64 + lane];
    atomicAdd(&psum[g * 64 + lane], s);
}

__global__ __launch_bounds__(128) void k_fc(const float* __restrict__ psum,
                                            const int* __restrict__ batch,
                                            const float* __restrict__ Wfc,
                                            const float* __restrict__ bfc,
                                            float* __restrict__ out) {
    __shared__ float meanv[64];
    __shared__ float red[2];
    int g = blockIdx.x;
    int c = threadIdx.x;
    int lo = lower_bound_batch(batch, g);
    int hi = lower_bound_batch(batch, g + 1);
    float icnt = 1.0f / fmaxf((float)(hi - lo), 1.0f);
    if (c < 64) meanv[c] = psum[g * 64 + c] * icnt;
    __syncthreads();
    float acc = bfc[c];
#pragma unroll
    for (int k = 0; k < 64; ++k) acc += meanv[k] * Wfc[k * 128 + c];
    float ss = acc * acc;
#pragma unroll
    for (int off = 32; off; off >>= 1) ss += __shfl_down(ss, off);
    if ((c & 63) == 0) red[c >> 6] = ss;
    __syncthreads();
    float norm = fmaxf(sqrtf(red[0] + red[1]), 1e-12f);
    out[g * 128 + c] = acc / norm;
}

extern "C" void kernel_launch(void* const* d_in, const int* in_sizes, int n_in,
                              void* d_out, int out_size, void* d_ws, size_t ws_size,
                              hipStream_t stream) {
    const float* x    = (const float*)d_in[0];
    const int*   ei   = (const int*)d_in[1];
    const int*   src  = ei;
    const int*   dst  = ei + NE;
    const int*   batch = (const int*)d_in[2];
    const float* Wl1 = (const float*)d_in[3];
    const float* bl1 = (const float*)d_in[4];
    const float* Wr1 = (const float*)d_in[5];
    const float* Wl2 = (const float*)d_in[6];
    const float* bl2 = (const float*)d_in[7];
    const float* Wr2 = (const float*)d_in[8];
    const float* Wl3 = (const float*)d_in[9];
    const float* bl3 = (const float*)d_in[10];
    const float* Wr3 = (const float*)d_in[11];
    const float* Wl4 = (const float*)d_in[12];
    const float* bl4 = (const float*)d_in[13];
    const float* Wr4 = (const float*)d_in[14];
    const float* Wfc = (const float*)d_in[15];
    const float* bfc = (const float*)d_in[16];
    float* out = (float*)d_out;

    // workspace layout
    _Float16* hA  = (_Float16*)d_ws;                  // [N,64] fp16
    _Float16* hB  = hA + (size_t)NN * 64;             // [N,64] fp16
    float* psum   = (float*)(hB + (size_t)NN * 64);   // [G,64]
    int*   off    = (int*)(psum + (size_t)NG * 64);   // [N+1]
    int*   bb     = off + NN + 1;                     // [NB1+1]
    int*   rowtot = bb + NB1 + 1;                     // [NB1]
    int*   rowbase = rowtot + NB1;                    // [NB1]
    int*   hist1  = rowbase + NB1;                    // [NB1*NBLK]
    int*   packed = hist1 + NB1 * NBLK;               // [E]
    int*   neigh  = packed + NE;                      // [E]

    hipMemsetAsync(psum, 0, (size_t)NG * 64 * sizeof(float), stream);

    // CSR build: atomic-free two-level bucket sort, fully parallel scan
    k_hist<<<NBLK, 256, 0, stream>>>(dst, hist1);
    k_rowsum<<<(NB1 + 3) / 4, 256, 0, stream>>>(hist1, rowtot);
    k_scanb<<<1, 1024, 0, stream>>>(rowtot, rowbase, bb);
    k_rowscan<<<(NB1 + 3) / 4, 256, 0, stream>>>(hist1, rowbase);
    k_scat<<<NBLK, 256, 0, stream>>>(src, dst, hist1, packed);
    k_bucket<<<NB1, 256, 0, stream>>>(packed, bb, neigh, off);

    // layer 1 (fused d=3 agg + transform), fp16 out
    k_l1<<<(NN + 3) / 4, 256, 0, stream>>>(off, neigh, x, Wl1, bl1, Wr1, hA);

    // layers 2-4: fused fp16 oct-gather + dot2 transform (ping-pong hA/hB)
    const int layerGrid = (NN + 7) / 8;
    k_layer<<<layerGrid, 512, 0, stream>>>(off, neigh, hA, Wl2, bl2, Wr2, hB);
    k_layer<<<layerGrid, 512, 0, stream>>>(off, neigh, hB, Wl3, bl3, Wr3, hA);
    k_layer<<<layerGrid, 512, 0, stream>>>(off, neigh, hA, Wl4, bl4, Wr4, hB);

    k_pool<<<NG * 8, 64, 0, stream>>>(hB, batch, psum);
    k_fc<<<NG, 128, 0, stream>>>(psum, batch, Wfc, bfc, out);
}

// Round 11
// 435.958 us; speedup vs baseline: 1.3983x; 1.0416x over previous
//
#include <hip/hip_runtime.h>

#define NN 100000
#define NE 3200000
#define NG 128
#define HID 64
#define OUTC 128

#define CHUNK 8192
#define NBLK 391                 // ceil(NE / CHUNK)
#define NB1 782                  // ceil(NN / 128) coarse buckets (dst >> 7)

typedef _Float16 half2v __attribute__((ext_vector_type(2)));
typedef _Float16 half4v __attribute__((ext_vector_type(4)));
typedef _Float16 half8v __attribute__((ext_vector_type(8)));
typedef float f32x4 __attribute__((ext_vector_type(4)));

// ---------------- P1: per-block coarse histogram (LDS atomics only) ----------------
__global__ __launch_bounds__(256) void k_hist(const int* __restrict__ dst,
                                              int* __restrict__ hist1) {
    __shared__ int h[NB1];
    for (int i = threadIdx.x; i < NB1; i += 256) h[i] = 0;
    __syncthreads();
    int base = blockIdx.x * CHUNK;
    int end = min(base + CHUNK, NE);
    for (int e = base + threadIdx.x; e < end; e += 256)
        atomicAdd(&h[dst[e] >> 7], 1);
    __syncthreads();
    for (int i = threadIdx.x; i < NB1; i += 256)
        hist1[i * NBLK + blockIdx.x] = h[i];
}

// ---------------- P2a: per-row totals (one wave per row) ----------------
__global__ __launch_bounds__(256) void k_rowsum(const int* __restrict__ hist1,
                                                int* __restrict__ rowtot) {
    int row = blockIdx.x * 4 + (threadIdx.x >> 6);
    int lane = threadIdx.x & 63;
    if (row >= NB1) return;
    int s = 0;
    for (int k = lane; k < NBLK; k += 64) s += hist1[row * NBLK + k];
#pragma unroll
    for (int m = 1; m < 64; m <<= 1) s += __shfl_xor(s, m);
    if (lane == 0) rowtot[row] = s;
}

// ---------------- P2b: small single-block scan of 782 row totals ----------------
__global__ __launch_bounds__(1024) void k_scanb(const int* __restrict__ rowtot,
                                                int* __restrict__ rowbase,
                                                int* __restrict__ bb) {
    __shared__ int sums[1024];
    int t = threadIdx.x;
    int v = (t < NB1) ? rowtot[t] : 0;
    sums[t] = v;
    __syncthreads();
    for (int d = 1; d < 1024; d <<= 1) {
        int u = (t >= d) ? sums[t - d] : 0;
        __syncthreads();
        sums[t] += u;
        __syncthreads();
    }
    if (t < NB1) {
        int base = sums[t] - v;   // exclusive
        rowbase[t] = base;
        bb[t] = base;
    }
    if (t == 0) bb[NB1] = NE;
}

// ---------------- P2c: per-row exclusive scan (one wave per row) ----------------
__global__ __launch_bounds__(256) void k_rowscan(int* __restrict__ hist1,
                                                 const int* __restrict__ rowbase) {
    int row = blockIdx.x * 4 + (threadIdx.x >> 6);
    int lane = threadIdx.x & 63;
    if (row >= NB1) return;
    int carry = rowbase[row];
    for (int k0 = 0; k0 < NBLK; k0 += 64) {
        int k = k0 + lane;
        int v = (k < NBLK) ? hist1[row * NBLK + k] : 0;
        int xv = v;
#pragma unroll
        for (int m = 1; m < 64; m <<= 1) {
            int y = __shfl_up(xv, m);
            if (lane >= m) xv += y;
        }
        int tot = __shfl(xv, 63);
        if (k < NBLK) hist1[row * NBLK + k] = xv - v + carry;
        carry += tot;
    }
}

// ---------------- P3: scatter into coarse buckets (LDS cursors) ----------------
__global__ __launch_bounds__(256) void k_scat(const int* __restrict__ src,
                                              const int* __restrict__ dst,
                                              const int* __restrict__ hist1,
                                              int* __restrict__ packed) {
    __shared__ int cur[NB1];
    for (int i = threadIdx.x; i < NB1; i += 256)
        cur[i] = hist1[i * NBLK + blockIdx.x];
    __syncthreads();
    int base = blockIdx.x * CHUNK;
    int end = min(base + CHUNK, NE);
    for (int e = base + threadIdx.x; e < end; e += 256) {
        int d = dst[e], s = src[e];
        int p = atomicAdd(&cur[d >> 7], 1);
        packed[p] = ((d & 127) << 17) | s;   // src < 2^17
    }
}

// ---------------- P4: within-bucket group by exact dst; emit neigh + off ----------------
__global__ __launch_bounds__(256) void k_bucket(const int* __restrict__ packed,
                                                const int* __restrict__ bb,
                                                int* __restrict__ neigh,
                                                int* __restrict__ off) {
    int b = blockIdx.x;
    int lo = bb[b], hi = bb[b + 1];
    __shared__ int cnt[128];
    __shared__ int pos[128];
    __shared__ int cur2[128];
    if (threadIdx.x < 128) cnt[threadIdx.x] = 0;
    __syncthreads();
    for (int i = lo + threadIdx.x; i < hi; i += 256)
        atomicAdd(&cnt[packed[i] >> 17], 1);
    __syncthreads();
    if (threadIdx.x == 0) {
        int run = lo;
        for (int j = 0; j < 128; ++j) { pos[j] = run; run += cnt[j]; }
    }
    __syncthreads();
    if (threadIdx.x < 128) {
        int node = b * 128 + threadIdx.x;
        if (node <= NN) off[node] = pos[threadIdx.x];
        cur2[threadIdx.x] = pos[threadIdx.x];
    }
    __syncthreads();
    for (int i = lo + threadIdx.x; i < hi; i += 256) {
        int p = packed[i];
        int j = p >> 17;
        int q = atomicAdd(&cur2[j], 1);
        neigh[q] = p & 0x1FFFF;
    }
}

// ---------------- layer 1: CSR mean-agg (d=3) + transform, fp16 out ----------------
__global__ __launch_bounds__(256) void k_l1(const int* __restrict__ off,
                                            const int* __restrict__ neigh,
                                            const float* __restrict__ x,
                                            const float* __restrict__ Wl,
                                            const float* __restrict__ bl,
                                            const float* __restrict__ Wr,
                                            _Float16* __restrict__ out) {
    int n = blockIdx.x * 4 + (threadIdx.x >> 6);
    int c = threadIdx.x & 63;
    if (n >= NN) return;
    int lo = off[n], hi = off[n + 1];
    float a0 = 0.f, a1 = 0.f, a2 = 0.f;
    for (int i = lo + c; i < hi; i += 64) {
        int s = neigh[i];
        a0 += x[s * 3 + 0];
        a1 += x[s * 3 + 1];
        a2 += x[s * 3 + 2];
    }
#pragma unroll
    for (int m = 1; m < 64; m <<= 1) {
        a0 += __shfl_xor(a0, m);
        a1 += __shfl_xor(a1, m);
        a2 += __shfl_xor(a2, m);
    }
    float ic = 1.0f / fmaxf((float)(hi - lo), 1.0f);
    a0 *= ic; a1 *= ic; a2 *= ic;
    float x0 = x[n * 3 + 0], x1 = x[n * 3 + 1], x2 = x[n * 3 + 2];
    float acc = bl[c]
              + a0 * Wl[0 * 64 + c] + a1 * Wl[1 * 64 + c] + a2 * Wl[2 * 64 + c]
              + x0 * Wr[0 * 64 + c] + x1 * Wr[1 * 64 + c] + x2 * Wr[2 * 64 + c];
    out[(size_t)n * 64 + c] = (_Float16)fmaxf(acc, 0.0f);
}

// ---------------- gather-only: quad-mode CSR mean (fp16 in/out) ----------------
// No LDS, no barrier: pure latency-hiding. mean must not alias h.
__global__ __launch_bounds__(512) void k_agg(const int* __restrict__ off,
                                             const int* __restrict__ neigh,
                                             const _Float16* __restrict__ h,
                                             _Float16* __restrict__ mean) {
    int li = threadIdx.x >> 6;
    int lane = threadIdx.x & 63;
    int g = lane >> 4;                    // neighbor slot within quad
    int q = lane & 15;                    // column quad (cols 4q..4q+3)
    int n = blockIdx.x * 8 + li;          // grid exact: 12500*8 = NN
    if (n >= NN) return;

    int lo = __builtin_amdgcn_readfirstlane(off[n]);
    int hi = __builtin_amdgcn_readfirstlane(off[n + 1]);
    int deg = hi - lo;
    const int* __restrict__ np = neigh + lo;
    const char* __restrict__ hb = (const char*)h;
    unsigned qoff = (unsigned)q << 3;

    float ax = 0.f, ay = 0.f, az = 0.f, aw = 0.f;
    int nq = deg >> 2;
#pragma unroll 4
    for (int i = 0; i < nq; ++i) {
        int s0 = np[4 * i + 0];           // uniform -> s_load
        int s1 = np[4 * i + 1];
        int s2 = np[4 * i + 2];
        int s3 = np[4 * i + 3];
        int s = (g & 2) ? ((g & 1) ? s3 : s2) : ((g & 1) ? s1 : s0);
        half4v v = *(const half4v*)(hb + (((unsigned)s << 7) | qoff));
        ax += (float)v.x; ay += (float)v.y; az += (float)v.z; aw += (float)v.w;
    }
    if (g == 0) {                         // tail: group 0 only
        for (int i = nq << 2; i < deg; ++i) {
            int s = np[i];
            half4v v = *(const half4v*)(hb + (((unsigned)s << 7) | qoff));
            ax += (float)v.x; ay += (float)v.y; az += (float)v.z; aw += (float)v.w;
        }
    }
#pragma unroll
    for (int m = 16; m <= 32; m <<= 1) {
        ax += __shfl_xor(ax, m);
        ay += __shfl_xor(ay, m);
        az += __shfl_xor(az, m);
        aw += __shfl_xor(aw, m);
    }
    if (g == 0) {
        float ic = 1.0f / fmaxf((float)deg, 1.0f);
        *(half4v*)&mean[(size_t)n * 64 + 4 * q] =
            half4v{(_Float16)(ax * ic), (_Float16)(ay * ic),
                   (_Float16)(az * ic), (_Float16)(aw * ic)};
    }
}

// ---------------- transform: [64 nodes][128]=[mean|root] x [128][64] via MFMA ----------------
// 256 thr = 4 waves; each wave does a 16x64 output tile (16 MFMA).
__global__ __launch_bounds__(256, 4) void k_xform(const _Float16* __restrict__ mean,
                                                  const _Float16* __restrict__ h,
                                                  const float* __restrict__ Wl,
                                                  const float* __restrict__ bl,
                                                  const float* __restrict__ Wr,
                                                  _Float16* __restrict__ out) {
    __shared__ __align__(16) _Float16 A[64][136];   // 17.4 KiB, padded rows

    const int tid  = threadIdx.x;
    const int li   = tid >> 6;
    const int lane = tid & 63;
    const int g    = lane >> 4;
    const int q    = lane & 15;
    const int nb   = blockIdx.x * 64;               // NN % 64 != 0 -> guard below

    // ---- B-frag + bias preload (stacked B[128][64] = [Wl;Wr]); overlaps staging ----
    half8v bfr[4][4];
    float bias[4];
#pragma unroll
    for (int t = 0; t < 4; ++t) {
        int c = 16 * t + q;
        bias[t] = bl[c];
#pragma unroll
        for (int s = 0; s < 4; ++s) {
#pragma unroll
            for (int e = 0; e < 8; ++e) {
                int kk = 32 * s + g * 8 + e;
                float w = (kk < 64) ? Wl[kk * 64 + c] : Wr[(kk - 64) * 64 + c];
                bfr[t][s][e] = (_Float16)w;
            }
        }
    }

    // ---- stage A: thread t -> node tid>>2, 64B chunk tid&3 (mean|mean|root|root) ----
    {
        int n = tid >> 2, c = tid & 3;
        int gn = nb + n;
        if (gn >= NN) gn = NN - 1;                  // clamp (writes unused rows)
        const _Float16* srcp = (c < 2) ? &mean[(size_t)gn * 64 + (c & 1) * 32]
                                       : &h[(size_t)gn * 64 + (c & 1) * 32];
        half8v v0 = *(const half8v*)(srcp + 0);
        half8v v1 = *(const half8v*)(srcp + 8);
        half8v v2 = *(const half8v*)(srcp + 16);
        half8v v3 = *(const half8v*)(srcp + 24);
        _Float16* dstp = &A[n][(c >> 1) * 64 + (c & 1) * 32];
        *(half8v*)(dstp + 0)  = v0;
        *(half8v*)(dstp + 8)  = v1;
        *(half8v*)(dstp + 16) = v2;
        *(half8v*)(dstp + 24) = v3;
    }
    __syncthreads();

    // ---- A-frags: m = q (node 16*li+q), k = 32s + 8g + e ----
    const int row = 16 * li + q;
    half8v a0 = *(const half8v*)&A[row][0 * 32 + 8 * g];
    half8v a1 = *(const half8v*)&A[row][1 * 32 + 8 * g];
    half8v a2 = *(const half8v*)&A[row][2 * 32 + 8 * g];
    half8v a3 = *(const half8v*)&A[row][3 * 32 + 8 * g];

    f32x4 acc[4];
#pragma unroll
    for (int t = 0; t < 4; ++t) {
        acc[t] = f32x4{0.f, 0.f, 0.f, 0.f};
        acc[t] = __builtin_amdgcn_mfma_f32_16x16x32_f16(a0, bfr[t][0], acc[t], 0, 0, 0);
        acc[t] = __builtin_amdgcn_mfma_f32_16x16x32_f16(a1, bfr[t][1], acc[t], 0, 0, 0);
        acc[t] = __builtin_amdgcn_mfma_f32_16x16x32_f16(a2, bfr[t][2], acc[t], 0, 0, 0);
        acc[t] = __builtin_amdgcn_mfma_f32_16x16x32_f16(a3, bfr[t][3], acc[t], 0, 0, 0);
    }

    // ---- epilogue: C row (node) = g*4+r, col = 16t+q; bias + relu + fp16 store ----
#pragma unroll
    for (int t = 0; t < 4; ++t) {
        int col = 16 * t + q;
#pragma unroll
        for (int r = 0; r < 4; ++r) {
            int gn = nb + 16 * li + g * 4 + r;
            if (gn < NN) {
                float val = acc[t][r] + bias[t];
                out[(size_t)gn * 64 + col] = (_Float16)fmaxf(val, 0.0f);
            }
        }
    }
}

// ---------------- pooling helpers ----------------
__device__ __forceinline__ int lower_bound_batch(const int* __restrict__ batch, int val) {
    int lo = 0, hi = NN;
    while (lo < hi) {
        int mid = (lo + hi) >> 1;
        if (batch[mid] < val) lo = mid + 1; else hi = mid;
    }
    return lo;
}

__global__ __launch_bounds__(64) void k_pool(const _Float16* __restrict__ h,
                                             const int* __restrict__ batch,
                                             float* __restrict__ psum) {
    int g = blockIdx.x >> 3;
    int part = blockIdx.x & 7;
    int lane = threadIdx.x;
    int lo = lower_bound_batch(batch, g);
    int hi = lower_bound_batch(batch, g + 1);
    float s = 0.0f;
    for (int n = lo + part; n < hi; n += 8) s += (float)h[(size_t)n * 64 + lane];
    atomicAdd(&psum[g * 64 + lane], s);
}

__global__ __launch_bounds__(128) void k_fc(const float* __restrict__ psum,
                                            const int* __restrict__ batch,
                                            const float* __restrict__ Wfc,
                                            const float* __restrict__ bfc,
                                            float* __restrict__ out) {
    __shared__ float meanv[64];
    __shared__ float red[2];
    int g = blockIdx.x;
    int c = threadIdx.x;
    int lo = lower_bound_batch(batch, g);
    int hi = lower_bound_batch(batch, g + 1);
    float icnt = 1.0f / fmaxf((float)(hi - lo), 1.0f);
    if (c < 64) meanv[c] = psum[g * 64 + c] * icnt;
    __syncthreads();
    float acc = bfc[c];
#pragma unroll
    for (int k = 0; k < 64; ++k) acc += meanv[k] * Wfc[k * 128 + c];
    float ss = acc * acc;
#pragma unroll
    for (int off = 32; off; off >>= 1) ss += __shfl_down(ss, off);
    if ((c & 63) == 0) red[c >> 6] = ss;
    __syncthreads();
    float norm = fmaxf(sqrtf(red[0] + red[1]), 1e-12f);
    out[g * 128 + c] = acc / norm;
}

extern "C" void kernel_launch(void* const* d_in, const int* in_sizes, int n_in,
                              void* d_out, int out_size, void* d_ws, size_t ws_size,
                              hipStream_t stream) {
    const float* x    = (const float*)d_in[0];
    const int*   ei   = (const int*)d_in[1];
    const int*   src  = ei;
    const int*   dst  = ei + NE;
    const int*   batch = (const int*)d_in[2];
    const float* Wl1 = (const float*)d_in[3];
    const float* bl1 = (const float*)d_in[4];
    const float* Wr1 = (const float*)d_in[5];
    const float* Wl2 = (const float*)d_in[6];
    const float* bl2 = (const float*)d_in[7];
    const float* Wr2 = (const float*)d_in[8];
    const float* Wl3 = (const float*)d_in[9];
    const float* bl3 = (const float*)d_in[10];
    const float* Wr3 = (const float*)d_in[11];
    const float* Wl4 = (const float*)d_in[12];
    const float* bl4 = (const float*)d_in[13];
    const float* Wr4 = (const float*)d_in[14];
    const float* Wfc = (const float*)d_in[15];
    const float* bfc = (const float*)d_in[16];
    float* out = (float*)d_out;

    // workspace layout
    _Float16* hA   = (_Float16*)d_ws;                 // [N,64] fp16
    _Float16* hB   = hA + (size_t)NN * 64;            // [N,64] fp16
    _Float16* mnb  = hB + (size_t)NN * 64;            // [N,64] fp16 mean buffer
    float* psum    = (float*)(mnb + (size_t)NN * 64); // [G,64]
    int*   off     = (int*)(psum + (size_t)NG * 64);  // [N+1]
    int*   bb      = off + NN + 1;                    // [NB1+1]
    int*   rowtot  = bb + NB1 + 1;                    // [NB1]
    int*   rowbase = rowtot + NB1;                    // [NB1]
    int*   hist1   = rowbase + NB1;                   // [NB1*NBLK]
    int*   packed  = hist1 + NB1 * NBLK;              // [E]
    int*   neigh   = packed + NE;                     // [E]

    hipMemsetAsync(psum, 0, (size_t)NG * 64 * sizeof(float), stream);

    // CSR build: atomic-free two-level bucket sort, fully parallel scan
    k_hist<<<NBLK, 256, 0, stream>>>(dst, hist1);
    k_rowsum<<<(NB1 + 3) / 4, 256, 0, stream>>>(hist1, rowtot);
    k_scanb<<<1, 1024, 0, stream>>>(rowtot, rowbase, bb);
    k_rowscan<<<(NB1 + 3) / 4, 256, 0, stream>>>(hist1, rowbase);
    k_scat<<<NBLK, 256, 0, stream>>>(src, dst, hist1, packed);
    k_bucket<<<NB1, 256, 0, stream>>>(packed, bb, neigh, off);

    // layer 1 (fused d=3 agg + transform), fp16 out
    k_l1<<<(NN + 3) / 4, 256, 0, stream>>>(off, neigh, x, Wl1, bl1, Wr1, hA);

    const int aggGrid = (NN + 7) / 8;
    const int xfGrid  = (NN + 63) / 64;

    // layers 2-4: gather-only + MFMA transform (ping-pong hA/hB)
    k_agg<<<aggGrid, 512, 0, stream>>>(off, neigh, hA, mnb);
    k_xform<<<xfGrid, 256, 0, stream>>>(mnb, hA, Wl2, bl2, Wr2, hB);

    k_agg<<<aggGrid, 512, 0, stream>>>(off, neigh, hB, mnb);
    k_xform<<<xfGrid, 256, 0, stream>>>(mnb, hB, Wl3, bl3, Wr3, hA);

    k_agg<<<aggGrid, 512, 0, stream>>>(off, neigh, hA, mnb);
    k_xform<<<xfGrid, 256, 0, stream>>>(mnb, hA, Wl4, bl4, Wr4, hB);

    k_pool<<<NG * 8, 64, 0, stream>>>(hB, batch, psum);
    k_fc<<<NG, 128, 0, stream>>>(psum, batch, Wfc, bfc, out);
}

// Round 12
// 378.056 us; speedup vs baseline: 1.6125x; 1.1532x over previous
//
#include <hip/hip_runtime.h>

#define NN 100000
#define NE 3200000
#define NG 128
#define HID 64
#define OUTC 128

#define CHUNK 8192
#define NBLK 391                 // ceil(NE / CHUNK)
#define NB1 782                  // ceil(NN / 128) coarse buckets (dst >> 7)

typedef _Float16 half2v __attribute__((ext_vector_type(2)));
typedef _Float16 half4v __attribute__((ext_vector_type(4)));
typedef _Float16 half8v __attribute__((ext_vector_type(8)));
typedef float f32x4 __attribute__((ext_vector_type(4)));

// ---------------- P1: per-block coarse histogram (LDS atomics only) ----------------
__global__ __launch_bounds__(256) void k_hist(const int* __restrict__ dst,
                                              int* __restrict__ hist1) {
    __shared__ int h[NB1];
    for (int i = threadIdx.x; i < NB1; i += 256) h[i] = 0;
    __syncthreads();
    int base = blockIdx.x * CHUNK;
    int end = min(base + CHUNK, NE);
    for (int e = base + threadIdx.x; e < end; e += 256)
        atomicAdd(&h[dst[e] >> 7], 1);
    __syncthreads();
    for (int i = threadIdx.x; i < NB1; i += 256)
        hist1[i * NBLK + blockIdx.x] = h[i];
}

// ---------------- P2a: per-row totals (one wave per row) ----------------
__global__ __launch_bounds__(256) void k_rowsum(const int* __restrict__ hist1,
                                                int* __restrict__ rowtot) {
    int row = blockIdx.x * 4 + (threadIdx.x >> 6);
    int lane = threadIdx.x & 63;
    if (row >= NB1) return;
    int s = 0;
    for (int k = lane; k < NBLK; k += 64) s += hist1[row * NBLK + k];
#pragma unroll
    for (int m = 1; m < 64; m <<= 1) s += __shfl_xor(s, m);
    if (lane == 0) rowtot[row] = s;
}

// ---------------- P2b: small single-block scan of 782 row totals ----------------
__global__ __launch_bounds__(1024) void k_scanb(const int* __restrict__ rowtot,
                                                int* __restrict__ rowbase,
                                                int* __restrict__ bb) {
    __shared__ int sums[1024];
    int t = threadIdx.x;
    int v = (t < NB1) ? rowtot[t] : 0;
    sums[t] = v;
    __syncthreads();
    for (int d = 1; d < 1024; d <<= 1) {
        int u = (t >= d) ? sums[t - d] : 0;
        __syncthreads();
        sums[t] += u;
        __syncthreads();
    }
    if (t < NB1) {
        int base = sums[t] - v;   // exclusive
        rowbase[t] = base;
        bb[t] = base;
    }
    if (t == 0) bb[NB1] = NE;
}

// ---------------- P2c: per-row exclusive scan (one wave per row) ----------------
__global__ __launch_bounds__(256) void k_rowscan(int* __restrict__ hist1,
                                                 const int* __restrict__ rowbase) {
    int row = blockIdx.x * 4 + (threadIdx.x >> 6);
    int lane = threadIdx.x & 63;
    if (row >= NB1) return;
    int carry = rowbase[row];
    for (int k0 = 0; k0 < NBLK; k0 += 64) {
        int k = k0 + lane;
        int v = (k < NBLK) ? hist1[row * NBLK + k] : 0;
        int xv = v;
#pragma unroll
        for (int m = 1; m < 64; m <<= 1) {
            int y = __shfl_up(xv, m);
            if (lane >= m) xv += y;
        }
        int tot = __shfl(xv, 63);
        if (k < NBLK) hist1[row * NBLK + k] = xv - v + carry;
        carry += tot;
    }
}

// ---------------- P3: scatter into coarse buckets (LDS cursors) ----------------
__global__ __launch_bounds__(256) void k_scat(const int* __restrict__ src,
                                              const int* __restrict__ dst,
                                              const int* __restrict__ hist1,
                                              int* __restrict__ packed) {
    __shared__ int cur[NB1];
    for (int i = threadIdx.x; i < NB1; i += 256)
        cur[i] = hist1[i * NBLK + blockIdx.x];
    __syncthreads();
    int base = blockIdx.x * CHUNK;
    int end = min(base + CHUNK, NE);
    for (int e = base + threadIdx.x; e < end; e += 256) {
        int d = dst[e], s = src[e];
        int p = atomicAdd(&cur[d >> 7], 1);
        packed[p] = ((d & 127) << 17) | s;   // src < 2^17
    }
}

// ---------------- P4: within-bucket group by exact dst; emit neigh + off ----------------
__global__ __launch_bounds__(256) void k_bucket(const int* __restrict__ packed,
                                                const int* __restrict__ bb,
                                                int* __restrict__ neigh,
                                                int* __restrict__ off) {
    int b = blockIdx.x;
    int lo = bb[b], hi = bb[b + 1];
    __shared__ int cnt[128];
    __shared__ int pos[128];
    __shared__ int cur2[128];
    if (threadIdx.x < 128) cnt[threadIdx.x] = 0;
    __syncthreads();
    for (int i = lo + threadIdx.x; i < hi; i += 256)
        atomicAdd(&cnt[packed[i] >> 17], 1);
    __syncthreads();
    if (threadIdx.x == 0) {
        int run = lo;
        for (int j = 0; j < 128; ++j) { pos[j] = run; run += cnt[j]; }
    }
    __syncthreads();
    if (threadIdx.x < 128) {
        int node = b * 128 + threadIdx.x;
        if (node <= NN) off[node] = pos[threadIdx.x];
        cur2[threadIdx.x] = pos[threadIdx.x];
    }
    __syncthreads();
    for (int i = lo + threadIdx.x; i < hi; i += 256) {
        int p = packed[i];
        int j = p >> 17;
        int q = atomicAdd(&cur2[j], 1);
        neigh[q] = p & 0x1FFFF;
    }
}

// ---------------- layer 1: CSR mean-agg (d=3) + transform, fp16 out ----------------
__global__ __launch_bounds__(256) void k_l1(const int* __restrict__ off,
                                            const int* __restrict__ neigh,
                                            const float* __restrict__ x,
                                            const float* __restrict__ Wl,
                                            const float* __restrict__ bl,
                                            const float* __restrict__ Wr,
                                            _Float16* __restrict__ out) {
    int n = blockIdx.x * 4 + (threadIdx.x >> 6);
    int c = threadIdx.x & 63;
    if (n >= NN) return;
    int lo = off[n], hi = off[n + 1];
    float a0 = 0.f, a1 = 0.f, a2 = 0.f;
    for (int i = lo + c; i < hi; i += 64) {
        int s = neigh[i];
        a0 += x[s * 3 + 0];
        a1 += x[s * 3 + 1];
        a2 += x[s * 3 + 2];
    }
#pragma unroll
    for (int m = 1; m < 64; m <<= 1) {
        a0 += __shfl_xor(a0, m);
        a1 += __shfl_xor(a1, m);
        a2 += __shfl_xor(a2, m);
    }
    float ic = 1.0f / fmaxf((float)(hi - lo), 1.0f);
    a0 *= ic; a1 *= ic; a2 *= ic;
    float x0 = x[n * 3 + 0], x1 = x[n * 3 + 1], x2 = x[n * 3 + 2];
    float acc = bl[c]
              + a0 * Wl[0 * 64 + c] + a1 * Wl[1 * 64 + c] + a2 * Wl[2 * 64 + c]
              + x0 * Wr[0 * 64 + c] + x1 * Wr[1 * 64 + c] + x2 * Wr[2 * 64 + c];
    out[(size_t)n * 64 + c] = (_Float16)fmaxf(acc, 0.0f);
}

// ---------------- gather-only: quad-mode CSR mean (fp16 in/out) ----------------
// No LDS, no barrier: pure latency-hiding. mean must not alias h.
__global__ __launch_bounds__(512) void k_agg(const int* __restrict__ off,
                                             const int* __restrict__ neigh,
                                             const _Float16* __restrict__ h,
                                             _Float16* __restrict__ mean) {
    int li = threadIdx.x >> 6;
    int lane = threadIdx.x & 63;
    int g = lane >> 4;                    // neighbor slot within quad
    int q = lane & 15;                    // column quad (cols 4q..4q+3)
    int n = blockIdx.x * 8 + li;          // grid exact: 12500*8 = NN
    if (n >= NN) return;

    int lo = __builtin_amdgcn_readfirstlane(off[n]);
    int hi = __builtin_amdgcn_readfirstlane(off[n + 1]);
    int deg = hi - lo;
    const int* __restrict__ np = neigh + lo;
    const char* __restrict__ hb = (const char*)h;
    unsigned qoff = (unsigned)q << 3;

    float ax = 0.f, ay = 0.f, az = 0.f, aw = 0.f;
    int nq = deg >> 2;
#pragma unroll 4
    for (int i = 0; i < nq; ++i) {
        int s0 = np[4 * i + 0];           // uniform -> s_load
        int s1 = np[4 * i + 1];
        int s2 = np[4 * i + 2];
        int s3 = np[4 * i + 3];
        int s = (g & 2) ? ((g & 1) ? s3 : s2) : ((g & 1) ? s1 : s0);
        half4v v = *(const half4v*)(hb + (((unsigned)s << 7) | qoff));
        ax += (float)v.x; ay += (float)v.y; az += (float)v.z; aw += (float)v.w;
    }
    if (g == 0) {                         // tail: group 0 only
        for (int i = nq << 2; i < deg; ++i) {
            int s = np[i];
            half4v v = *(const half4v*)(hb + (((unsigned)s << 7) | qoff));
            ax += (float)v.x; ay += (float)v.y; az += (float)v.z; aw += (float)v.w;
        }
    }
#pragma unroll
    for (int m = 16; m <= 32; m <<= 1) {
        ax += __shfl_xor(ax, m);
        ay += __shfl_xor(ay, m);
        az += __shfl_xor(az, m);
        aw += __shfl_xor(aw, m);
    }
    if (g == 0) {
        float ic = 1.0f / fmaxf((float)deg, 1.0f);
        *(half4v*)&mean[(size_t)n * 64 + 4 * q] =
            half4v{(_Float16)(ax * ic), (_Float16)(ay * ic),
                   (_Float16)(az * ic), (_Float16)(aw * ic)};
    }
}

// ---------------- transform: [128 nodes][128]=[mean|root] x [128][64] via MFMA ----------------
// 512 thr = 8 waves; each wave does a 16x64 output tile (16 MFMA).
// W staged coalesced into LDS (transposed) once per block; B-frags via ds_read_b128.
__global__ __launch_bounds__(512) void k_xform(const _Float16* __restrict__ mean,
                                               const _Float16* __restrict__ h,
                                               const float* __restrict__ Wl,
                                               const float* __restrict__ bl,
                                               const float* __restrict__ Wr,
                                               _Float16* __restrict__ out) {
    __shared__ __align__(16) _Float16 A[128][136];   // 34.8 KiB, padded rows
    __shared__ __align__(16) _Float16 Wt[64][136];   // 17.4 KiB: W^T [c][kk], padded

    const int tid  = threadIdx.x;
    const int li   = tid >> 6;
    const int lane = tid & 63;
    const int g    = lane >> 4;
    const int q    = lane & 15;
    const int nb   = blockIdx.x * 128;

    // ---- stage Wt = [Wl;Wr]^T as f16 (coalesced f32 reads, once per block) ----
    for (int i = tid; i < 8192; i += 512) {
        int kk = i >> 6;       // 0..127
        int c  = i & 63;
        float w = (kk < 64) ? Wl[kk * 64 + c] : Wr[(kk - 64) * 64 + c];
        Wt[c][kk] = (_Float16)w;
    }

    // ---- stage A: thread t -> node tid>>2, 64B chunk tid&3 (mean|mean|root|root) ----
    {
        int n = tid >> 2, c = tid & 3;
        int gn = nb + n;
        if (gn >= NN) gn = NN - 1;                   // clamp (rows unused)
        const _Float16* srcp = (c < 2) ? &mean[(size_t)gn * 64 + (c & 1) * 32]
                                       : &h[(size_t)gn * 64 + (c & 1) * 32];
        half8v v0 = *(const half8v*)(srcp + 0);
        half8v v1 = *(const half8v*)(srcp + 8);
        half8v v2 = *(const half8v*)(srcp + 16);
        half8v v3 = *(const half8v*)(srcp + 24);
        _Float16* dstp = &A[n][(c >> 1) * 64 + (c & 1) * 32];
        *(half8v*)(dstp + 0)  = v0;
        *(half8v*)(dstp + 8)  = v1;
        *(half8v*)(dstp + 16) = v2;
        *(half8v*)(dstp + 24) = v3;
    }
    __syncthreads();

    // ---- B-frags from LDS: lane(g,q) tile t step s -> Wt[16t+q][32s+8g..+8] ----
    half8v bfr[4][4];
    float bias[4];
#pragma unroll
    for (int t = 0; t < 4; ++t) {
        bias[t] = bl[16 * t + q];
#pragma unroll
        for (int s = 0; s < 4; ++s)
            bfr[t][s] = *(const half8v*)&Wt[16 * t + q][32 * s + 8 * g];
    }

    // ---- A-frags: m = q (row 16*li+q), k = 32s + 8g + e ----
    const int row = 16 * li + q;
    half8v a0 = *(const half8v*)&A[row][0 * 32 + 8 * g];
    half8v a1 = *(const half8v*)&A[row][1 * 32 + 8 * g];
    half8v a2 = *(const half8v*)&A[row][2 * 32 + 8 * g];
    half8v a3 = *(const half8v*)&A[row][3 * 32 + 8 * g];

    f32x4 acc[4];
#pragma unroll
    for (int t = 0; t < 4; ++t) {
        acc[t] = f32x4{0.f, 0.f, 0.f, 0.f};
        acc[t] = __builtin_amdgcn_mfma_f32_16x16x32_f16(a0, bfr[t][0], acc[t], 0, 0, 0);
        acc[t] = __builtin_amdgcn_mfma_f32_16x16x32_f16(a1, bfr[t][1], acc[t], 0, 0, 0);
        acc[t] = __builtin_amdgcn_mfma_f32_16x16x32_f16(a2, bfr[t][2], acc[t], 0, 0, 0);
        acc[t] = __builtin_amdgcn_mfma_f32_16x16x32_f16(a3, bfr[t][3], acc[t], 0, 0, 0);
    }

    // ---- epilogue: C row (node) = g*4+r, col = 16t+q; bias + relu + fp16 store ----
#pragma unroll
    for (int t = 0; t < 4; ++t) {
        int col = 16 * t + q;
#pragma unroll
        for (int r = 0; r < 4; ++r) {
            int gn = nb + 16 * li + g * 4 + r;
            if (gn < NN) {
                float val = acc[t][r] + bias[t];
                out[(size_t)gn * 64 + col] = (_Float16)fmaxf(val, 0.0f);
            }
        }
    }
}

// ---------------- pooling helpers ----------------
__device__ __forceinline__ int lower_bound_batch(const int* __restrict__ batch, int val) {
    int lo = 0, hi = NN;
    while (lo < hi) {
        int mid = (lo + hi) >> 1;
        if (batch[mid] < val) lo = mid + 1; else hi = mid;
    }
    return lo;
}

__global__ __launch_bounds__(64) void k_pool(const _Float16* __restrict__ h,
                                             const int* __restrict__ batch,
                                             float* __restrict__ psum) {
    int g = blockIdx.x >> 3;
    int part = blockIdx.x & 7;
    int lane = threadIdx.x;
    int lo = lower_bound_batch(batch, g);
    int hi = lower_bound_batch(batch, g + 1);
    float s = 0.0f;
    for (int n = lo + part; n < hi; n += 8) s += (float)h[(size_t)n * 64 + lane];
    atomicAdd(&psum[g * 64 + lane], s);
}

__global__ __launch_bounds__(128) void k_fc(const float* __restrict__ psum,
                                            const int* __restrict__ batch,
                                            const float* __restrict__ Wfc,
                                            const float* __restrict__ bfc,
                                            float* __restrict__ out) {
    __shared__ float meanv[64];
    __shared__ float red[2];
    int g = blockIdx.x;
    int c = threadIdx.x;
    int lo = lower_bound_batch(batch, g);
    int hi = lower_bound_batch(batch, g + 1);
    float icnt = 1.0f / fmaxf((float)(hi - lo), 1.0f);
    if (c < 64) meanv[c] = psum[g * 64 + c] * icnt;
    __syncthreads();
    float acc = bfc[c];
#pragma unroll
    for (int k = 0; k < 64; ++k) acc += meanv[k] * Wfc[k * 128 + c];
    float ss = acc * acc;
#pragma unroll
    for (int off = 32; off; off >>= 1) ss += __shfl_down(ss, off);
    if ((c & 63) == 0) red[c >> 6] = ss;
    __syncthreads();
    float norm = fmaxf(sqrtf(red[0] + red[1]), 1e-12f);
    out[g * 128 + c] = acc / norm;
}

extern "C" void kernel_launch(void* const* d_in, const int* in_sizes, int n_in,
                              void* d_out, int out_size, void* d_ws, size_t ws_size,
                              hipStream_t stream) {
    const float* x    = (const float*)d_in[0];
    const int*   ei   = (const int*)d_in[1];
    const int*   src  = ei;
    const int*   dst  = ei + NE;
    const int*   batch = (const int*)d_in[2];
    const float* Wl1 = (const float*)d_in[3];
    const float* bl1 = (const float*)d_in[4];
    const float* Wr1 = (const float*)d_in[5];
    const float* Wl2 = (const float*)d_in[6];
    const float* bl2 = (const float*)d_in[7];
    const float* Wr2 = (const float*)d_in[8];
    const float* Wl3 = (const float*)d_in[9];
    const float* bl3 = (const float*)d_in[10];
    const float* Wr3 = (const float*)d_in[11];
    const float* Wl4 = (const float*)d_in[12];
    const float* bl4 = (const float*)d_in[13];
    const float* Wr4 = (const float*)d_in[14];
    const float* Wfc = (const float*)d_in[15];
    const float* bfc = (const float*)d_in[16];
    float* out = (float*)d_out;

    // workspace layout
    _Float16* hA   = (_Float16*)d_ws;                 // [N,64] fp16
    _Float16* hB   = hA + (size_t)NN * 64;            // [N,64] fp16
    _Float16* mnb  = hB + (size_t)NN * 64;            // [N,64] fp16 mean buffer
    float* psum    = (float*)(mnb + (size_t)NN * 64); // [G,64]
    int*   off     = (int*)(psum + (size_t)NG * 64);  // [N+1]
    int*   bb      = off + NN + 1;                    // [NB1+1]
    int*   rowtot  = bb + NB1 + 1;                    // [NB1]
    int*   rowbase = rowtot + NB1;                    // [NB1]
    int*   hist1   = rowbase + NB1;                   // [NB1*NBLK]
    int*   packed  = hist1 + NB1 * NBLK;              // [E]
    int*   neigh   = packed + NE;                     // [E]

    hipMemsetAsync(psum, 0, (size_t)NG * 64 * sizeof(float), stream);

    // CSR build: atomic-free two-level bucket sort, fully parallel scan
    k_hist<<<NBLK, 256, 0, stream>>>(dst, hist1);
    k_rowsum<<<(NB1 + 3) / 4, 256, 0, stream>>>(hist1, rowtot);
    k_scanb<<<1, 1024, 0, stream>>>(rowtot, rowbase, bb);
    k_rowscan<<<(NB1 + 3) / 4, 256, 0, stream>>>(hist1, rowbase);
    k_scat<<<NBLK, 256, 0, stream>>>(src, dst, hist1, packed);
    k_bucket<<<NB1, 256, 0, stream>>>(packed, bb, neigh, off);

    // layer 1 (fused d=3 agg + transform), fp16 out
    k_l1<<<(NN + 3) / 4, 256, 0, stream>>>(off, neigh, x, Wl1, bl1, Wr1, hA);

    const int aggGrid = (NN + 7) / 8;
    const int xfGrid  = (NN + 127) / 128;

    // layers 2-4: gather-only + MFMA transform (ping-pong hA/hB)
    k_agg<<<aggGrid, 512, 0, stream>>>(off, neigh, hA, mnb);
    k_xform<<<xfGrid, 512, 0, stream>>>(mnb, hA, Wl2, bl2, Wr2, hB);

    k_agg<<<aggGrid, 512, 0, stream>>>(off, neigh, hB, mnb);
    k_xform<<<xfGrid, 512, 0, stream>>>(mnb, hB, Wl3, bl3, Wr3, hA);

    k_agg<<<aggGrid, 512, 0, stream>>>(off, neigh, hA, mnb);
    k_xform<<<xfGrid, 512, 0, stream>>>(mnb, hA, Wl4, bl4, Wr4, hB);

    k_pool<<<NG * 8, 64, 0, stream>>>(hB, batch, psum);
    k_fc<<<NG, 128, 0, stream>>>(psum, batch, Wfc, bfc, out);
}

// Round 13
// 372.246 us; speedup vs baseline: 1.6377x; 1.0156x over previous
//
#include <hip/hip_runtime.h>

#define NN 100000
#define NE 3200000
#define NG 128
#define HID 64
#define OUTC 128

#define CHUNK 8192
#define NBLK 391                 // ceil(NE / CHUNK)
#define NB1 782                  // ceil(NN / 128) coarse buckets (dst >> 7)

typedef _Float16 half2v __attribute__((ext_vector_type(2)));
typedef _Float16 half4v __attribute__((ext_vector_type(4)));
typedef _Float16 half8v __attribute__((ext_vector_type(8)));
typedef float f32x4 __attribute__((ext_vector_type(4)));

// ---------------- P1: per-block coarse histogram (LDS atomics only) ----------------
__global__ __launch_bounds__(256) void k_hist(const int* __restrict__ dst,
                                              int* __restrict__ hist1) {
    __shared__ int h[NB1];
    for (int i = threadIdx.x; i < NB1; i += 256) h[i] = 0;
    __syncthreads();
    int base = blockIdx.x * CHUNK;
    int end = min(base + CHUNK, NE);
    for (int e = base + threadIdx.x; e < end; e += 256)
        atomicAdd(&h[dst[e] >> 7], 1);
    __syncthreads();
    for (int i = threadIdx.x; i < NB1; i += 256)
        hist1[i * NBLK + blockIdx.x] = h[i];
}

// ---------------- P2a: per-row totals (one wave per row) ----------------
__global__ __launch_bounds__(256) void k_rowsum(const int* __restrict__ hist1,
                                                int* __restrict__ rowtot) {
    int row = blockIdx.x * 4 + (threadIdx.x >> 6);
    int lane = threadIdx.x & 63;
    if (row >= NB1) return;
    int s = 0;
    for (int k = lane; k < NBLK; k += 64) s += hist1[row * NBLK + k];
#pragma unroll
    for (int m = 1; m < 64; m <<= 1) s += __shfl_xor(s, m);
    if (lane == 0) rowtot[row] = s;
}

// ---------------- P2b: small single-block scan of 782 row totals ----------------
__global__ __launch_bounds__(1024) void k_scanb(const int* __restrict__ rowtot,
                                                int* __restrict__ rowbase,
                                                int* __restrict__ bb) {
    __shared__ int sums[1024];
    int t = threadIdx.x;
    int v = (t < NB1) ? rowtot[t] : 0;
    sums[t] = v;
    __syncthreads();
    for (int d = 1; d < 1024; d <<= 1) {
        int u = (t >= d) ? sums[t - d] : 0;
        __syncthreads();
        sums[t] += u;
        __syncthreads();
    }
    if (t < NB1) {
        int base = sums[t] - v;   // exclusive
        rowbase[t] = base;
        bb[t] = base;
    }
    if (t == 0) bb[NB1] = NE;
}

// ---------------- P2c: per-row exclusive scan (one wave per row) ----------------
__global__ __launch_bounds__(256) void k_rowscan(int* __restrict__ hist1,
                                                 const int* __restrict__ rowbase) {
    int row = blockIdx.x * 4 + (threadIdx.x >> 6);
    int lane = threadIdx.x & 63;
    if (row >= NB1) return;
    int carry = rowbase[row];
    for (int k0 = 0; k0 < NBLK; k0 += 64) {
        int k = k0 + lane;
        int v = (k < NBLK) ? hist1[row * NBLK + k] : 0;
        int xv = v;
#pragma unroll
        for (int m = 1; m < 64; m <<= 1) {
            int y = __shfl_up(xv, m);
            if (lane >= m) xv += y;
        }
        int tot = __shfl(xv, 63);
        if (k < NBLK) hist1[row * NBLK + k] = xv - v + carry;
        carry += tot;
    }
}

// ---------------- P3: scatter into coarse buckets (LDS cursors) ----------------
__global__ __launch_bounds__(256) void k_scat(const int* __restrict__ src,
                                              const int* __restrict__ dst,
                                              const int* __restrict__ hist1,
                                              int* __restrict__ packed) {
    __shared__ int cur[NB1];
    for (int i = threadIdx.x; i < NB1; i += 256)
        cur[i] = hist1[i * NBLK + blockIdx.x];
    __syncthreads();
    int base = blockIdx.x * CHUNK;
    int end = min(base + CHUNK, NE);
    for (int e = base + threadIdx.x; e < end; e += 256) {
        int d = dst[e], s = src[e];
        int p = atomicAdd(&cur[d >> 7], 1);
        packed[p] = ((d & 127) << 17) | s;   // src < 2^17
    }
}

// ---------------- P4: within-bucket group by exact dst; emit neigh + off ----------------
__global__ __launch_bounds__(256) void k_bucket(const int* __restrict__ packed,
                                                const int* __restrict__ bb,
                                                int* __restrict__ neigh,
                                                int* __restrict__ off) {
    int b = blockIdx.x;
    int lo = bb[b], hi = bb[b + 1];
    __shared__ int cnt[128];
    __shared__ int pos[128];
    __shared__ int cur2[128];
    if (threadIdx.x < 128) cnt[threadIdx.x] = 0;
    __syncthreads();
    for (int i = lo + threadIdx.x; i < hi; i += 256)
        atomicAdd(&cnt[packed[i] >> 17], 1);
    __syncthreads();
    if (threadIdx.x == 0) {
        int run = lo;
        for (int j = 0; j < 128; ++j) { pos[j] = run; run += cnt[j]; }
    }
    __syncthreads();
    if (threadIdx.x < 128) {
        int node = b * 128 + threadIdx.x;
        if (node <= NN) off[node] = pos[threadIdx.x];
        cur2[threadIdx.x] = pos[threadIdx.x];
    }
    __syncthreads();
    for (int i = lo + threadIdx.x; i < hi; i += 256) {
        int p = packed[i];
        int j = p >> 17;
        int q = atomicAdd(&cur2[j], 1);
        neigh[q] = p & 0x1FFFF;
    }
}

// ---------------- layer 1: CSR mean-agg (d=3) + transform, fp16 out ----------------
__global__ __launch_bounds__(256) void k_l1(const int* __restrict__ off,
                                            const int* __restrict__ neigh,
                                            const float* __restrict__ x,
                                            const float* __restrict__ Wl,
                                            const float* __restrict__ bl,
                                            const float* __restrict__ Wr,
                                            _Float16* __restrict__ out) {
    int n = blockIdx.x * 4 + (threadIdx.x >> 6);
    int c = threadIdx.x & 63;
    if (n >= NN) return;
    int lo = off[n], hi = off[n + 1];
    float a0 = 0.f, a1 = 0.f, a2 = 0.f;
    for (int i = lo + c; i < hi; i += 64) {
        int s = neigh[i];
        a0 += x[s * 3 + 0];
        a1 += x[s * 3 + 1];
        a2 += x[s * 3 + 2];
    }
#pragma unroll
    for (int m = 1; m < 64; m <<= 1) {
        a0 += __shfl_xor(a0, m);
        a1 += __shfl_xor(a1, m);
        a2 += __shfl_xor(a2, m);
    }
    float ic = 1.0f / fmaxf((float)(hi - lo), 1.0f);
    a0 *= ic; a1 *= ic; a2 *= ic;
    float x0 = x[n * 3 + 0], x1 = x[n * 3 + 1], x2 = x[n * 3 + 2];
    float acc = bl[c]
              + a0 * Wl[0 * 64 + c] + a1 * Wl[1 * 64 + c] + a2 * Wl[2 * 64 + c]
              + x0 * Wr[0 * 64 + c] + x1 * Wr[1 * 64 + c] + x2 * Wr[2 * 64 + c];
    out[(size_t)n * 64 + c] = (_Float16)fmaxf(acc, 0.0f);
}

// ---------------- gather-only: quad-mode CSR mean, 8-deep load pipeline ----------------
// No LDS, no barrier. Explicit 8-batch of loads into registers before any
// accumulation: ~40 VGPRs (<=64 keeps full 32 waves/CU), 8 loads in flight.
__global__ __launch_bounds__(512, 8) void k_agg(const int* __restrict__ off,
                                                const int* __restrict__ neigh,
                                                const _Float16* __restrict__ h,
                                                _Float16* __restrict__ mean) {
    int li = threadIdx.x >> 6;
    int lane = threadIdx.x & 63;
    int g = lane >> 4;                    // neighbor slot within quad
    int q = lane & 15;                    // column quad (cols 4q..4q+3)
    int n = blockIdx.x * 8 + li;          // grid exact: 12500*8 = NN
    if (n >= NN) return;

    int lo = __builtin_amdgcn_readfirstlane(off[n]);
    int hi = __builtin_amdgcn_readfirstlane(off[n + 1]);
    int deg = hi - lo;
    const int* __restrict__ np = neigh + lo;
    const char* __restrict__ hb = (const char*)h;
    unsigned qoff = (unsigned)q << 3;

    float ax = 0.f, ay = 0.f, az = 0.f, aw = 0.f;
    int nq = deg >> 2;
    int i = 0;

    // 8-deep: 8 independent loads issued before first accumulate
    for (; i + 8 <= nq; i += 8) {
        half4v v0, v1, v2, v3, v4, v5, v6, v7;
#pragma unroll
        for (int j = 0; j < 8; ++j) {
            int s0 = np[4 * (i + j) + 0];
            int s1 = np[4 * (i + j) + 1];
            int s2 = np[4 * (i + j) + 2];
            int s3 = np[4 * (i + j) + 3];
            int s = (g & 2) ? ((g & 1) ? s3 : s2) : ((g & 1) ? s1 : s0);
            half4v v = *(const half4v*)(hb + (((unsigned)s << 7) | qoff));
            if (j == 0) v0 = v; else if (j == 1) v1 = v; else if (j == 2) v2 = v;
            else if (j == 3) v3 = v; else if (j == 4) v4 = v; else if (j == 5) v5 = v;
            else if (j == 6) v6 = v; else v7 = v;
        }
        ax += ((float)v0.x + (float)v1.x) + ((float)v2.x + (float)v3.x)
            + ((float)v4.x + (float)v5.x) + ((float)v6.x + (float)v7.x);
        ay += ((float)v0.y + (float)v1.y) + ((float)v2.y + (float)v3.y)
            + ((float)v4.y + (float)v5.y) + ((float)v6.y + (float)v7.y);
        az += ((float)v0.z + (float)v1.z) + ((float)v2.z + (float)v3.z)
            + ((float)v4.z + (float)v5.z) + ((float)v6.z + (float)v7.z);
        aw += ((float)v0.w + (float)v1.w) + ((float)v2.w + (float)v3.w)
            + ((float)v4.w + (float)v5.w) + ((float)v6.w + (float)v7.w);
    }
    // 4-deep
    if (i + 4 <= nq) {
        half4v v0, v1, v2, v3;
#pragma unroll
        for (int j = 0; j < 4; ++j) {
            int s0 = np[4 * (i + j) + 0];
            int s1 = np[4 * (i + j) + 1];
            int s2 = np[4 * (i + j) + 2];
            int s3 = np[4 * (i + j) + 3];
            int s = (g & 2) ? ((g & 1) ? s3 : s2) : ((g & 1) ? s1 : s0);
            half4v v = *(const half4v*)(hb + (((unsigned)s << 7) | qoff));
            if (j == 0) v0 = v; else if (j == 1) v1 = v; else if (j == 2) v2 = v; else v3 = v;
        }
        ax += ((float)v0.x + (float)v1.x) + ((float)v2.x + (float)v3.x);
        ay += ((float)v0.y + (float)v1.y) + ((float)v2.y + (float)v3.y);
        az += ((float)v0.z + (float)v1.z) + ((float)v2.z + (float)v3.z);
        aw += ((float)v0.w + (float)v1.w) + ((float)v2.w + (float)v3.w);
        i += 4;
    }
    // singles
    for (; i < nq; ++i) {
        int s0 = np[4 * i + 0];
        int s1 = np[4 * i + 1];
        int s2 = np[4 * i + 2];
        int s3 = np[4 * i + 3];
        int s = (g & 2) ? ((g & 1) ? s3 : s2) : ((g & 1) ? s1 : s0);
        half4v v = *(const half4v*)(hb + (((unsigned)s << 7) | qoff));
        ax += (float)v.x; ay += (float)v.y; az += (float)v.z; aw += (float)v.w;
    }
    // tail (deg%4): group 0 only
    if (g == 0) {
        for (int t = nq << 2; t < deg; ++t) {
            int s = np[t];
            half4v v = *(const half4v*)(hb + (((unsigned)s << 7) | qoff));
            ax += (float)v.x; ay += (float)v.y; az += (float)v.z; aw += (float)v.w;
        }
    }
#pragma unroll
    for (int m = 16; m <= 32; m <<= 1) {
        ax += __shfl_xor(ax, m);
        ay += __shfl_xor(ay, m);
        az += __shfl_xor(az, m);
        aw += __shfl_xor(aw, m);
    }
    if (g == 0) {
        float ic = 1.0f / fmaxf((float)deg, 1.0f);
        *(half4v*)&mean[(size_t)n * 64 + 4 * q] =
            half4v{(_Float16)(ax * ic), (_Float16)(ay * ic),
                   (_Float16)(az * ic), (_Float16)(aw * ic)};
    }
}

// ---------------- transform: [128 nodes][128]=[mean|root] x [128][64] via MFMA ----------------
__global__ __launch_bounds__(512) void k_xform(const _Float16* __restrict__ mean,
                                               const _Float16* __restrict__ h,
                                               const float* __restrict__ Wl,
                                               const float* __restrict__ bl,
                                               const float* __restrict__ Wr,
                                               _Float16* __restrict__ out) {
    __shared__ __align__(16) _Float16 A[128][136];   // 34.8 KiB, padded rows
    __shared__ __align__(16) _Float16 Wt[64][136];   // 17.4 KiB: W^T [c][kk], padded

    const int tid  = threadIdx.x;
    const int li   = tid >> 6;
    const int lane = tid & 63;
    const int g    = lane >> 4;
    const int q    = lane & 15;
    const int nb   = blockIdx.x * 128;

    // ---- stage Wt = [Wl;Wr]^T as f16 (coalesced f32 reads, once per block) ----
    for (int i = tid; i < 8192; i += 512) {
        int kk = i >> 6;       // 0..127
        int c  = i & 63;
        float w = (kk < 64) ? Wl[kk * 64 + c] : Wr[(kk - 64) * 64 + c];
        Wt[c][kk] = (_Float16)w;
    }

    // ---- stage A: thread t -> node tid>>2, 64B chunk tid&3 (mean|mean|root|root) ----
    {
        int n = tid >> 2, c = tid & 3;
        int gn = nb + n;
        if (gn >= NN) gn = NN - 1;                   // clamp (rows unused)
        const _Float16* srcp = (c < 2) ? &mean[(size_t)gn * 64 + (c & 1) * 32]
                                       : &h[(size_t)gn * 64 + (c & 1) * 32];
        half8v v0 = *(const half8v*)(srcp + 0);
        half8v v1 = *(const half8v*)(srcp + 8);
        half8v v2 = *(const half8v*)(srcp + 16);
        half8v v3 = *(const half8v*)(srcp + 24);
        _Float16* dstp = &A[n][(c >> 1) * 64 + (c & 1) * 32];
        *(half8v*)(dstp + 0)  = v0;
        *(half8v*)(dstp + 8)  = v1;
        *(half8v*)(dstp + 16) = v2;
        *(half8v*)(dstp + 24) = v3;
    }
    __syncthreads();

    // ---- B-frags from LDS: lane(g,q) tile t step s -> Wt[16t+q][32s+8g..+8] ----
    half8v bfr[4][4];
    float bias[4];
#pragma unroll
    for (int t = 0; t < 4; ++t) {
        bias[t] = bl[16 * t + q];
#pragma unroll
        for (int s = 0; s < 4; ++s)
            bfr[t][s] = *(const half8v*)&Wt[16 * t + q][32 * s + 8 * g];
    }

    // ---- A-frags: m = q (row 16*li+q), k = 32s + 8g + e ----
    const int row = 16 * li + q;
    half8v a0 = *(const half8v*)&A[row][0 * 32 + 8 * g];
    half8v a1 = *(const half8v*)&A[row][1 * 32 + 8 * g];
    half8v a2 = *(const half8v*)&A[row][2 * 32 + 8 * g];
    half8v a3 = *(const half8v*)&A[row][3 * 32 + 8 * g];

    f32x4 acc[4];
#pragma unroll
    for (int t = 0; t < 4; ++t) {
        acc[t] = f32x4{0.f, 0.f, 0.f, 0.f};
        acc[t] = __builtin_amdgcn_mfma_f32_16x16x32_f16(a0, bfr[t][0], acc[t], 0, 0, 0);
        acc[t] = __builtin_amdgcn_mfma_f32_16x16x32_f16(a1, bfr[t][1], acc[t], 0, 0, 0);
        acc[t] = __builtin_amdgcn_mfma_f32_16x16x32_f16(a2, bfr[t][2], acc[t], 0, 0, 0);
        acc[t] = __builtin_amdgcn_mfma_f32_16x16x32_f16(a3, bfr[t][3], acc[t], 0, 0, 0);
    }

    // ---- epilogue: C row (node) = g*4+r, col = 16t+q; bias + relu + fp16 store ----
#pragma unroll
    for (int t = 0; t < 4; ++t) {
        int col = 16 * t + q;
#pragma unroll
        for (int r = 0; r < 4; ++r) {
            int gn = nb + 16 * li + g * 4 + r;
            if (gn < NN) {
                float val = acc[t][r] + bias[t];
                out[(size_t)gn * 64 + col] = (_Float16)fmaxf(val, 0.0f);
            }
        }
    }
}

// ---------------- pooling helpers ----------------
__device__ __forceinline__ int lower_bound_batch(const int* __restrict__ batch, int val) {
    int lo = 0, hi = NN;
    while (lo < hi) {
        int mid = (lo + hi) >> 1;
        if (batch[mid] < val) lo = mid + 1; else hi = mid;
    }
    return lo;
}

__global__ __launch_bounds__(64) void k_pool(const _Float16* __restrict__ h,
                                             const int* __restrict__ batch,
                                             float* __restrict__ psum) {
    int g = blockIdx.x >> 3;
    int part = blockIdx.x & 7;
    int lane = threadIdx.x;
    int lo = lower_bound_batch(batch, g);
    int hi = lower_bound_batch(batch, g + 1);
    float s = 0.0f;
    for (int n = lo + part; n < hi; n += 8) s += (float)h[(size_t)n * 64 + lane];
    atomicAdd(&psum[g * 64 + lane], s);
}

__global__ __launch_bounds__(128) void k_fc(const float* __restrict__ psum,
                                            const int* __restrict__ batch,
                                            const float* __restrict__ Wfc,
                                            const float* __restrict__ bfc,
                                            float* __restrict__ out) {
    __shared__ float meanv[64];
    __shared__ float red[2];
    int g = blockIdx.x;
    int c = threadIdx.x;
    int lo = lower_bound_batch(batch, g);
    int hi = lower_bound_batch(batch, g + 1);
    float icnt = 1.0f / fmaxf((float)(hi - lo), 1.0f);
    if (c < 64) meanv[c] = psum[g * 64 + c] * icnt;
    __syncthreads();
    float acc = bfc[c];
#pragma unroll
    for (int k = 0; k < 64; ++k) acc += meanv[k] * Wfc[k * 128 + c];
    float ss = acc * acc;
#pragma unroll
    for (int off = 32; off; off >>= 1) ss += __shfl_down(ss, off);
    if ((c & 63) == 0) red[c >> 6] = ss;
    __syncthreads();
    float norm = fmaxf(sqrtf(red[0] + red[1]), 1e-12f);
    out[g * 128 + c] = acc / norm;
}

extern "C" void kernel_launch(void* const* d_in, const int* in_sizes, int n_in,
                              void* d_out, int out_size, void* d_ws, size_t ws_size,
                              hipStream_t stream) {
    const float* x    = (const float*)d_in[0];
    const int*   ei   = (const int*)d_in[1];
    const int*   src  = ei;
    const int*   dst  = ei + NE;
    const int*   batch = (const int*)d_in[2];
    const float* Wl1 = (const float*)d_in[3];
    const float* bl1 = (const float*)d_in[4];
    const float* Wr1 = (const float*)d_in[5];
    const float* Wl2 = (const float*)d_in[6];
    const float* bl2 = (const float*)d_in[7];
    const float* Wr2 = (const float*)d_in[8];
    const float* Wl3 = (const float*)d_in[9];
    const float* bl3 = (const float*)d_in[10];
    const float* Wr3 = (const float*)d_in[11];
    const float* Wl4 = (const float*)d_in[12];
    const float* bl4 = (const float*)d_in[13];
    const float* Wr4 = (const float*)d_in[14];
    const float* Wfc = (const float*)d_in[15];
    const float* bfc = (const float*)d_in[16];
    float* out = (float*)d_out;

    // workspace layout
    _Float16* hA   = (_Float16*)d_ws;                 // [N,64] fp16
    _Float16* hB   = hA + (size_t)NN * 64;            // [N,64] fp16
    _Float16* mnb  = hB + (size_t)NN * 64;            // [N,64] fp16 mean buffer
    float* psum    = (float*)(mnb + (size_t)NN * 64); // [G,64]
    int*   off     = (int*)(psum + (size_t)NG * 64);  // [N+1]
    int*   bb      = off + NN + 1;                    // [NB1+1]
    int*   rowtot  = bb + NB1 + 1;                    // [NB1]
    int*   rowbase = rowtot + NB1;                    // [NB1]
    int*   hist1   = rowbase + NB1;                   // [NB1*NBLK]
    int*   packed  = hist1 + NB1 * NBLK;              // [E]
    int*   neigh   = packed + NE;                     // [E]

    hipMemsetAsync(psum, 0, (size_t)NG * 64 * sizeof(float), stream);

    // CSR build: atomic-free two-level bucket sort, fully parallel scan
    k_hist<<<NBLK, 256, 0, stream>>>(dst, hist1);
    k_rowsum<<<(NB1 + 3) / 4, 256, 0, stream>>>(hist1, rowtot);
    k_scanb<<<1, 1024, 0, stream>>>(rowtot, rowbase, bb);
    k_rowscan<<<(NB1 + 3) / 4, 256, 0, stream>>>(hist1, rowbase);
    k_scat<<<NBLK, 256, 0, stream>>>(src, dst, hist1, packed);
    k_bucket<<<NB1, 256, 0, stream>>>(packed, bb, neigh, off);

    // layer 1 (fused d=3 agg + transform), fp16 out
    k_l1<<<(NN + 3) / 4, 256, 0, stream>>>(off, neigh, x, Wl1, bl1, Wr1, hA);

    const int aggGrid = (NN + 7) / 8;
    const int xfGrid  = (NN + 127) / 128;

    // layers 2-4: gather-only + MFMA transform (ping-pong hA/hB)
    k_agg<<<aggGrid, 512, 0, stream>>>(off, neigh, hA, mnb);
    k_xform<<<xfGrid, 512, 0, stream>>>(mnb, hA, Wl2, bl2, Wr2, hB);

    k_agg<<<aggGrid, 512, 0, stream>>>(off, neigh, hB, mnb);
    k_xform<<<xfGrid, 512, 0, stream>>>(mnb, hB, Wl3, bl3, Wr3, hA);

    k_agg<<<aggGrid, 512, 0, stream>>>(off, neigh, hA, mnb);
    k_xform<<<xfGrid, 512, 0, stream>>>(mnb, hA, Wl4, bl4, Wr4, hB);

    k_pool<<<NG * 8, 64, 0, stream>>>(hB, batch, psum);
    k_fc<<<NG, 128, 0, stream>>>(psum, batch, Wfc, bfc, out);
}

// Round 14
// 368.753 us; speedup vs baseline: 1.6532x; 1.0095x over previous
//
#include <hip/hip_runtime.h>

#define NN 100000
#define NE 3200000
#define NG 128
#define HID 64
#define OUTC 128

#define CHUNK 8192
#define NBLK 391                 // ceil(NE / CHUNK)
#define NB1 782                  // ceil(NN / 128) coarse buckets (dst >> 7)

typedef _Float16 half2v __attribute__((ext_vector_type(2)));
typedef _Float16 half4v __attribute__((ext_vector_type(4)));
typedef _Float16 half8v __attribute__((ext_vector_type(8)));
typedef float f32x4 __attribute__((ext_vector_type(4)));

// ---------------- P1: per-block coarse histogram (LDS atomics only) ----------------
__global__ __launch_bounds__(1024) void k_hist(const int* __restrict__ dst,
                                               int* __restrict__ hist1) {
    __shared__ int h[NB1];
    for (int i = threadIdx.x; i < NB1; i += 1024) h[i] = 0;
    __syncthreads();
    int base = blockIdx.x * CHUNK;
    int end = min(base + CHUNK, NE);
    for (int e = base + threadIdx.x; e < end; e += 1024)
        atomicAdd(&h[dst[e] >> 7], 1);
    __syncthreads();
    for (int i = threadIdx.x; i < NB1; i += 1024)
        hist1[i * NBLK + blockIdx.x] = h[i];
}

// ---------------- P2a: per-row totals (one wave per row) ----------------
__global__ __launch_bounds__(256) void k_rowsum(const int* __restrict__ hist1,
                                                int* __restrict__ rowtot) {
    int row = blockIdx.x * 4 + (threadIdx.x >> 6);
    int lane = threadIdx.x & 63;
    if (row >= NB1) return;
    int s = 0;
    for (int k = lane; k < NBLK; k += 64) s += hist1[row * NBLK + k];
#pragma unroll
    for (int m = 1; m < 64; m <<= 1) s += __shfl_xor(s, m);
    if (lane == 0) rowtot[row] = s;
}

// ---------------- P2b: small single-block scan of 782 row totals ----------------
__global__ __launch_bounds__(1024) void k_scanb(const int* __restrict__ rowtot,
                                                int* __restrict__ rowbase,
                                                int* __restrict__ bb) {
    __shared__ int sums[1024];
    int t = threadIdx.x;
    int v = (t < NB1) ? rowtot[t] : 0;
    sums[t] = v;
    __syncthreads();
    for (int d = 1; d < 1024; d <<= 1) {
        int u = (t >= d) ? sums[t - d] : 0;
        __syncthreads();
        sums[t] += u;
        __syncthreads();
    }
    if (t < NB1) {
        int base = sums[t] - v;   // exclusive
        rowbase[t] = base;
        bb[t] = base;
    }
    if (t == 0) bb[NB1] = NE;
}

// ---------------- P2c: per-row exclusive scan (one wave per row) ----------------
__global__ __launch_bounds__(256) void k_rowscan(int* __restrict__ hist1,
                                                 const int* __restrict__ rowbase) {
    int row = blockIdx.x * 4 + (threadIdx.x >> 6);
    int lane = threadIdx.x & 63;
    if (row >= NB1) return;
    int carry = rowbase[row];
    for (int k0 = 0; k0 < NBLK; k0 += 64) {
        int k = k0 + lane;
        int v = (k < NBLK) ? hist1[row * NBLK + k] : 0;
        int xv = v;
#pragma unroll
        for (int m = 1; m < 64; m <<= 1) {
            int y = __shfl_up(xv, m);
            if (lane >= m) xv += y;
        }
        int tot = __shfl(xv, 63);
        if (k < NBLK) hist1[row * NBLK + k] = xv - v + carry;
        carry += tot;
    }
}

// ---------------- P3: scatter into coarse buckets (LDS cursors) ----------------
__global__ __launch_bounds__(1024) void k_scat(const int* __restrict__ src,
                                               const int* __restrict__ dst,
                                               const int* __restrict__ hist1,
                                               int* __restrict__ packed) {
    __shared__ int cur[NB1];
    for (int i = threadIdx.x; i < NB1; i += 1024)
        cur[i] = hist1[i * NBLK + blockIdx.x];
    __syncthreads();
    int base = blockIdx.x * CHUNK;
    int end = min(base + CHUNK, NE);
    for (int e = base + threadIdx.x; e < end; e += 1024) {
        int d = dst[e], s = src[e];
        int p = atomicAdd(&cur[d >> 7], 1);
        packed[p] = ((d & 127) << 17) | s;   // src < 2^17
    }
}

// ---------------- P4: within-bucket group by exact dst; emit neigh + off ----------------
__global__ __launch_bounds__(512) void k_bucket(const int* __restrict__ packed,
                                                const int* __restrict__ bb,
                                                int* __restrict__ neigh,
                                                int* __restrict__ off) {
    int b = blockIdx.x;
    int lo = bb[b], hi = bb[b + 1];
    __shared__ int cnt[128];
    __shared__ int pos[128];
    __shared__ int cur2[128];
    if (threadIdx.x < 128) cnt[threadIdx.x] = 0;
    __syncthreads();
    for (int i = lo + threadIdx.x; i < hi; i += 512)
        atomicAdd(&cnt[packed[i] >> 17], 1);
    __syncthreads();
    if (threadIdx.x == 0) {
        int run = lo;
        for (int j = 0; j < 128; ++j) { pos[j] = run; run += cnt[j]; }
    }
    __syncthreads();
    if (threadIdx.x < 128) {
        int node = b * 128 + threadIdx.x;
        if (node <= NN) off[node] = pos[threadIdx.x];
        cur2[threadIdx.x] = pos[threadIdx.x];
    }
    __syncthreads();
    for (int i = lo + threadIdx.x; i < hi; i += 512) {
        int p = packed[i];
        int j = p >> 17;
        int q = atomicAdd(&cur2[j], 1);
        neigh[q] = p & 0x1FFFF;
    }
}

// ---------------- layer 1: CSR mean-agg (d=3) + transform, fp16 out ----------------
__global__ __launch_bounds__(256) void k_l1(const int* __restrict__ off,
                                            const int* __restrict__ neigh,
                                            const float* __restrict__ x,
                                            const float* __restrict__ Wl,
                                            const float* __restrict__ bl,
                                            const float* __restrict__ Wr,
                                            _Float16* __restrict__ out) {
    int n = blockIdx.x * 4 + (threadIdx.x >> 6);
    int c = threadIdx.x & 63;
    if (n >= NN) return;
    int lo = off[n], hi = off[n + 1];
    float a0 = 0.f, a1 = 0.f, a2 = 0.f;
    for (int i = lo + c; i < hi; i += 64) {
        int s = neigh[i];
        a0 += x[s * 3 + 0];
        a1 += x[s * 3 + 1];
        a2 += x[s * 3 + 2];
    }
#pragma unroll
    for (int m = 1; m < 64; m <<= 1) {
        a0 += __shfl_xor(a0, m);
        a1 += __shfl_xor(a1, m);
        a2 += __shfl_xor(a2, m);
    }
    float ic = 1.0f / fmaxf((float)(hi - lo), 1.0f);
    a0 *= ic; a1 *= ic; a2 *= ic;
    float x0 = x[n * 3 + 0], x1 = x[n * 3 + 1], x2 = x[n * 3 + 2];
    float acc = bl[c]
              + a0 * Wl[0 * 64 + c] + a1 * Wl[1 * 64 + c] + a2 * Wl[2 * 64 + c]
              + x0 * Wr[0 * 64 + c] + x1 * Wr[1 * 64 + c] + x2 * Wr[2 * 64 + c];
    out[(size_t)n * 64 + c] = (_Float16)fmaxf(acc, 0.0f);
}

// ---------------- gather-only: quad-mode CSR mean (fp16 in/out) ----------------
__global__ __launch_bounds__(512, 8) void k_agg(const int* __restrict__ off,
                                                const int* __restrict__ neigh,
                                                const _Float16* __restrict__ h,
                                                _Float16* __restrict__ mean) {
    int li = threadIdx.x >> 6;
    int lane = threadIdx.x & 63;
    int g = lane >> 4;                    // neighbor slot within quad
    int q = lane & 15;                    // column quad (cols 4q..4q+3)
    int n = blockIdx.x * 8 + li;          // grid exact: 12500*8 = NN
    if (n >= NN) return;

    int lo = __builtin_amdgcn_readfirstlane(off[n]);
    int hi = __builtin_amdgcn_readfirstlane(off[n + 1]);
    int deg = hi - lo;
    const int* __restrict__ np = neigh + lo;
    const char* __restrict__ hb = (const char*)h;
    unsigned qoff = (unsigned)q << 3;

    float ax = 0.f, ay = 0.f, az = 0.f, aw = 0.f;
    int nq = deg >> 2;
#pragma unroll 4
    for (int i = 0; i < nq; ++i) {
        int s0 = np[4 * i + 0];           // uniform -> s_load
        int s1 = np[4 * i + 1];
        int s2 = np[4 * i + 2];
        int s3 = np[4 * i + 3];
        int s = (g & 2) ? ((g & 1) ? s3 : s2) : ((g & 1) ? s1 : s0);
        half4v v = *(const half4v*)(hb + (((unsigned)s << 7) | qoff));
        ax += (float)v.x; ay += (float)v.y; az += (float)v.z; aw += (float)v.w;
    }
    if (g == 0) {                         // tail: group 0 only
        for (int i = nq << 2; i < deg; ++i) {
            int s = np[i];
            half4v v = *(const half4v*)(hb + (((unsigned)s << 7) | qoff));
            ax += (float)v.x; ay += (float)v.y; az += (float)v.z; aw += (float)v.w;
        }
    }
#pragma unroll
    for (int m = 16; m <= 32; m <<= 1) {
        ax += __shfl_xor(ax, m);
        ay += __shfl_xor(ay, m);
        az += __shfl_xor(az, m);
        aw += __shfl_xor(aw, m);
    }
    if (g == 0) {
        float ic = 1.0f / fmaxf((float)deg, 1.0f);
        *(half4v*)&mean[(size_t)n * 64 + 4 * q] =
            half4v{(_Float16)(ax * ic), (_Float16)(ay * ic),
                   (_Float16)(az * ic), (_Float16)(aw * ic)};
    }
}

// ---------------- transform: [128 nodes][128]=[mean|root] x [128][64] via MFMA ----------------
__global__ __launch_bounds__(512) void k_xform(const _Float16* __restrict__ mean,
                                               const _Float16* __restrict__ h,
                                               const float* __restrict__ Wl,
                                               const float* __restrict__ bl,
                                               const float* __restrict__ Wr,
                                               _Float16* __restrict__ out) {
    __shared__ __align__(16) _Float16 A[128][136];   // 34.8 KiB, padded rows
    __shared__ __align__(16) _Float16 Wt[64][136];   // 17.4 KiB: W^T [c][kk], padded

    const int tid  = threadIdx.x;
    const int li   = tid >> 6;
    const int lane = tid & 63;
    const int g    = lane >> 4;
    const int q    = lane & 15;
    const int nb   = blockIdx.x * 128;

    // ---- stage Wt = [Wl;Wr]^T as f16 (coalesced f32 reads, once per block) ----
    for (int i = tid; i < 8192; i += 512) {
        int kk = i >> 6;       // 0..127
        int c  = i & 63;
        float w = (kk < 64) ? Wl[kk * 64 + c] : Wr[(kk - 64) * 64 + c];
        Wt[c][kk] = (_Float16)w;
    }

    // ---- stage A: thread t -> node tid>>2, 64B chunk tid&3 (mean|mean|root|root) ----
    {
        int n = tid >> 2, c = tid & 3;
        int gn = nb + n;
        if (gn >= NN) gn = NN - 1;                   // clamp (rows unused)
        const _Float16* srcp = (c < 2) ? &mean[(size_t)gn * 64 + (c & 1) * 32]
                                       : &h[(size_t)gn * 64 + (c & 1) * 32];
        half8v v0 = *(const half8v*)(srcp + 0);
        half8v v1 = *(const half8v*)(srcp + 8);
        half8v v2 = *(const half8v*)(srcp + 16);
        half8v v3 = *(const half8v*)(srcp + 24);
        _Float16* dstp = &A[n][(c >> 1) * 64 + (c & 1) * 32];
        *(half8v*)(dstp + 0)  = v0;
        *(half8v*)(dstp + 8)  = v1;
        *(half8v*)(dstp + 16) = v2;
        *(half8v*)(dstp + 24) = v3;
    }
    __syncthreads();

    // ---- B-frags from LDS: lane(g,q) tile t step s -> Wt[16t+q][32s+8g..+8] ----
    half8v bfr[4][4];
    float bias[4];
#pragma unroll
    for (int t = 0; t < 4; ++t) {
        bias[t] = bl[16 * t + q];
#pragma unroll
        for (int s = 0; s < 4; ++s)
            bfr[t][s] = *(const half8v*)&Wt[16 * t + q][32 * s + 8 * g];
    }

    // ---- A-frags: m = q (row 16*li+q), k = 32s + 8g + e ----
    const int row = 16 * li + q;
    half8v a0 = *(const half8v*)&A[row][0 * 32 + 8 * g];
    half8v a1 = *(const half8v*)&A[row][1 * 32 + 8 * g];
    half8v a2 = *(const half8v*)&A[row][2 * 32 + 8 * g];
    half8v a3 = *(const half8v*)&A[row][3 * 32 + 8 * g];

    f32x4 acc[4];
#pragma unroll
    for (int t = 0; t < 4; ++t) {
        acc[t] = f32x4{0.f, 0.f, 0.f, 0.f};
        acc[t] = __builtin_amdgcn_mfma_f32_16x16x32_f16(a0, bfr[t][0], acc[t], 0, 0, 0);
        acc[t] = __builtin_amdgcn_mfma_f32_16x16x32_f16(a1, bfr[t][1], acc[t], 0, 0, 0);
        acc[t] = __builtin_amdgcn_mfma_f32_16x16x32_f16(a2, bfr[t][2], acc[t], 0, 0, 0);
        acc[t] = __builtin_amdgcn_mfma_f32_16x16x32_f16(a3, bfr[t][3], acc[t], 0, 0, 0);
    }

    // ---- epilogue: C row (node) = g*4+r, col = 16t+q; bias + relu + fp16 store ----
#pragma unroll
    for (int t = 0; t < 4; ++t) {
        int col = 16 * t + q;
#pragma unroll
        for (int r = 0; r < 4; ++r) {
            int gn = nb + 16 * li + g * 4 + r;
            if (gn < NN) {
                float val = acc[t][r] + bias[t];
                out[(size_t)gn * 64 + col] = (_Float16)fmaxf(val, 0.0f);
            }
        }
    }
}

// ---------------- pooling helpers ----------------
__device__ __forceinline__ int lower_bound_batch(const int* __restrict__ batch, int val) {
    int lo = 0, hi = NN;
    while (lo < hi) {
        int mid = (lo + hi) >> 1;
        if (batch[mid] < val) lo = mid + 1; else hi = mid;
    }
    return lo;
}

__global__ __launch_bounds__(64) void k_pool(const _Float16* __restrict__ h,
                                             const int* __restrict__ batch,
                                             float* __restrict__ psum) {
    int g = blockIdx.x >> 3;
    int part = blockIdx.x & 7;
    int lane = threadIdx.x;
    int lo = lower_bound_batch(batch, g);
    int hi = lower_bound_batch(batch, g + 1);
    float s = 0.0f;
    for (int n = lo + part; n < hi; n += 8) s += (float)h[(size_t)n * 64 + lane];
    atomicAdd(&psum[g * 64 + lane], s);
}

__global__ __launch_bounds__(128) void k_fc(const float* __restrict__ psum,
                                            const int* __restrict__ batch,
                                            const float* __restrict__ Wfc,
                                            const float* __restrict__ bfc,
                                            float* __restrict__ out) {
    __shared__ float meanv[64];
    __shared__ float red[2];
    int g = blockIdx.x;
    int c = threadIdx.x;
    int lo = lower_bound_batch(batch, g);
    int hi = lower_bound_batch(batch, g + 1);
    float icnt = 1.0f / fmaxf((float)(hi - lo), 1.0f);
    if (c < 64) meanv[c] = psum[g * 64 + c] * icnt;
    __syncthreads();
    float acc = bfc[c];
#pragma unroll
    for (int k = 0; k < 64; ++k) acc += meanv[k] * Wfc[k * 128 + c];
    float ss = acc * acc;
#pragma unroll
    for (int off = 32; off; off >>= 1) ss += __shfl_down(ss, off);
    if ((c & 63) == 0) red[c >> 6] = ss;
    __syncthreads();
    float norm = fmaxf(sqrtf(red[0] + red[1]), 1e-12f);
    out[g * 128 + c] = acc / norm;
}

extern "C" void kernel_launch(void* const* d_in, const int* in_sizes, int n_in,
                              void* d_out, int out_size, void* d_ws, size_t ws_size,
                              hipStream_t stream) {
    const float* x    = (const float*)d_in[0];
    const int*   ei   = (const int*)d_in[1];
    const int*   src  = ei;
    const int*   dst  = ei + NE;
    const int*   batch = (const int*)d_in[2];
    const float* Wl1 = (const float*)d_in[3];
    const float* bl1 = (const float*)d_in[4];
    const float* Wr1 = (const float*)d_in[5];
    const float* Wl2 = (const float*)d_in[6];
    const float* bl2 = (const float*)d_in[7];
    const float* Wr2 = (const float*)d_in[8];
    const float* Wl3 = (const float*)d_in[9];
    const float* bl3 = (const float*)d_in[10];
    const float* Wr3 = (const float*)d_in[11];
    const float* Wl4 = (const float*)d_in[12];
    const float* bl4 = (const float*)d_in[13];
    const float* Wr4 = (const float*)d_in[14];
    const float* Wfc = (const float*)d_in[15];
    const float* bfc = (const float*)d_in[16];
    float* out = (float*)d_out;

    // workspace layout
    _Float16* hA   = (_Float16*)d_ws;                 // [N,64] fp16
    _Float16* hB   = hA + (size_t)NN * 64;            // [N,64] fp16
    _Float16* mnb  = hB + (size_t)NN * 64;            // [N,64] fp16 mean buffer
    float* psum    = (float*)(mnb + (size_t)NN * 64); // [G,64]
    int*   off     = (int*)(psum + (size_t)NG * 64);  // [N+1]
    int*   bb      = off + NN + 1;                    // [NB1+1]
    int*   rowtot  = bb + NB1 + 1;                    // [NB1]
    int*   rowbase = rowtot + NB1;                    // [NB1]
    int*   hist1   = rowbase + NB1;                   // [NB1*NBLK]
    int*   packed  = hist1 + NB1 * NBLK;              // [E]
    int*   neigh   = packed + NE;                     // [E]

    hipMemsetAsync(psum, 0, (size_t)NG * 64 * sizeof(float), stream);

    // CSR build: atomic-free two-level bucket sort, fully parallel scan
    k_hist<<<NBLK, 1024, 0, stream>>>(dst, hist1);
    k_rowsum<<<(NB1 + 3) / 4, 256, 0, stream>>>(hist1, rowtot);
    k_scanb<<<1, 1024, 0, stream>>>(rowtot, rowbase, bb);
    k_rowscan<<<(NB1 + 3) / 4, 256, 0, stream>>>(hist1, rowbase);
    k_scat<<<NBLK, 1024, 0, stream>>>(src, dst, hist1, packed);
    k_bucket<<<NB1, 512, 0, stream>>>(packed, bb, neigh, off);

    // layer 1 (fused d=3 agg + transform), fp16 out
    k_l1<<<(NN + 3) / 4, 256, 0, stream>>>(off, neigh, x, Wl1, bl1, Wr1, hA);

    const int aggGrid = (NN + 7) / 8;
    const int xfGrid  = (NN + 127) / 128;

    // layers 2-4: gather-only + MFMA transform (ping-pong hA/hB)
    k_agg<<<aggGrid, 512, 0, stream>>>(off, neigh, hA, mnb);
    k_xform<<<xfGrid, 512, 0, stream>>>(mnb, hA, Wl2, bl2, Wr2, hB);

    k_agg<<<aggGrid, 512, 0, stream>>>(off, neigh, hB, mnb);
    k_xform<<<xfGrid, 512, 0, stream>>>(mnb, hB, Wl3, bl3, Wr3, hA);

    k_agg<<<aggGrid, 512, 0, stream>>>(off, neigh, hA, mnb);
    k_xform<<<xfGrid, 512, 0, stream>>>(mnb, hA, Wl4, bl4, Wr4, hB);

    k_pool<<<NG * 8, 64, 0, stream>>>(hB, batch, psum);
    k_fc<<<NG, 128, 0, stream>>>(psum, batch, Wfc, bfc, out);
}